// Round 13
// baseline (942.827 us; speedup 1.0000x reference)
//
#include <hip/hip_runtime.h>
#include <hip/hip_bf16.h>
#include <cstdint>
#include <cstddef>

// Problem constants (match reference)
#define B_CL   8
#define NPTS   2048
#define S1CNT  1024
#define S2CNT  256
#define KNBR   64

typedef unsigned short ushort;
typedef __attribute__((ext_vector_type(8))) short short8b;  // 8 bf16 = MFMA A/B frag
typedef __attribute__((ext_vector_type(4))) float f32x4;    // MFMA C/D frag

__device__ __forceinline__ ushort f2bf(float f) {
    union { __hip_bfloat16 h; ushort u; } v;
    v.h = __float2bfloat16(f);
    return v.u;
}
__device__ __forceinline__ float bf2f(ushort u) {
    return __uint_as_float(((unsigned)u) << 16);
}
__device__ __forceinline__ short8b ldfrag(const ushort* p) {
    return *(const short8b*)p;
}
__device__ __forceinline__ f32x4 mfma16(short8b a, short8b b, f32x4 c) {
    return __builtin_amdgcn_mfma_f32_16x16x32_bf16(a, b, c, 0, 0, 0);
}

// Exact f32 squared distance in the reference's summation order.
__device__ __forceinline__ float dist2_exact(float ax, float ay, float az,
                                             float bx, float by, float bz) {
    float dx = __fsub_rn(ax, bx);
    float dy = __fsub_rn(ay, by);
    float dz = __fsub_rn(az, bz);
    return __fadd_rn(__fadd_rn(__fmul_rn(dx, dx), __fmul_rn(dy, dy)), __fmul_rn(dz, dz));
}

// 64-lane max-reduce of a u64 key via DPP. Result valid in lane 63.
__device__ __forceinline__ unsigned long long wave_max_u64(unsigned long long k) {
#define DPP_STEP(CTRL) {                                                            \
    unsigned lo = (unsigned)k, hi = (unsigned)(k >> 32);                            \
    unsigned nlo = (unsigned)__builtin_amdgcn_update_dpp((int)lo, (int)lo, CTRL,    \
                                                         0xf, 0xf, false);          \
    unsigned nhi = (unsigned)__builtin_amdgcn_update_dpp((int)hi, (int)hi, CTRL,    \
                                                         0xf, 0xf, false);          \
    unsigned long long nk = ((unsigned long long)nhi << 32) | nlo;                  \
    if (nk > k) k = nk;                                                             \
}
    DPP_STEP(0x111);  // row_shr:1
    DPP_STEP(0x112);  // row_shr:2
    DPP_STEP(0x114);  // row_shr:4
    DPP_STEP(0x118);  // row_shr:8
    DPP_STEP(0x142);  // row_bcast:15
    DPP_STEP(0x143);  // row_bcast:31
#undef DPP_STEP
    return k;
}

// ---------------------------------------------------------------------------
// Farthest point sampling PAIR body: 512-thread block = 2 clouds x 4 waves.
// Each 256-thread half runs the EXACT round-7 algorithm (measured best) on
// its own cloud; the only coupling is the shared __syncthreads. Mechanism:
// each SIMD now hosts 2 waves (one per cloud) whose issue fills the other's
// dependent-latency stalls (DPP chain, LDS round trips) — wave-level TLP,
// not thread-level interleave (which round 8 showed serializes issue).
// Selection is bit-exact per cloud: d2 in reference op order, key=(d2,~idx).
// ---------------------------------------------------------------------------
template <int N, int S>
__device__ __forceinline__ void fps_pair_body(const float* __restrict__ pos,
                                              float* __restrict__ cpos,
                                              int b0, char* smem) {
    constexpr int PPT = N / 256;
    float* pxa = (float*)smem;                  // [2][N]
    float* pya = pxa + 2 * N;                   // [2][N]
    float* pza = pya + 2 * N;                   // [2][N]
    float* sela = pza + 2 * N;                  // [2][S*3]
    unsigned long long* kbuf = (unsigned long long*)(sela + 2 * S * 3); // [2][2][4]

    const int tid = threadIdx.x;    // 0..511
    const int c   = tid >> 8;       // cloud within block
    const int lt  = tid & 255;      // thread within cloud
    const int wl  = lt >> 6;        // wave within cloud (0..3)
    const int b   = b0 + c;

    float* px = pxa + c * N;
    float* py = pya + c * N;
    float* pz = pza + c * N;
    float* sel = sela + c * S * 3;
    const float* P = pos + (size_t)b * N * 3;

    float ox[PPT], oy[PPT], oz[PPT], d[PPT];
    #pragma unroll
    for (int j = 0; j < PPT; ++j) {
        int idx = lt + 256 * j;
        float x = P[idx * 3 + 0];
        float y = P[idx * 3 + 1];
        float z = P[idx * 3 + 2];
        px[idx] = x; py[idx] = y; pz[idx] = z;
        ox[j] = x; oy[j] = y; oz[j] = z;
        d[j] = 1e30f;
    }
    __syncthreads();

    float cx = px[0], cy = py[0], cz = pz[0];
    if (lt == 0) { sel[0] = cx; sel[1] = cy; sel[2] = cz; }

    for (int i = 1; i < S; ++i) {
        // update distances with current point; local argmax (strict > keeps
        // the first/min index since idx increases with j)
        float bv = -1.0f;
        int   bi = 0;
        #pragma unroll
        for (int j = 0; j < PPT; ++j) {
            int idx = lt + 256 * j;
            float dd = dist2_exact(ox[j], oy[j], oz[j], cx, cy, cz);
            float nd = fminf(d[j], dd);
            d[j] = nd;
            if (nd > bv) { bv = nd; bi = idx; }
        }
        // pack (d2, ~idx): u64 max == (max d2, then min idx). d2 >= 0 so the
        // f32 bit pattern is order-preserving.
        unsigned long long key =
            ((unsigned long long)__float_as_uint(bv) << 32) | (unsigned)(~bi);
        key = wave_max_u64(key);

        const int par = i & 1;
        if ((lt & 63) == 63) kbuf[(par * 2 + c) * 4 + wl] = key;
        __syncthreads();

        // every thread resolves its cloud's winner redundantly (no 2nd
        // barrier; parity double-buffer makes next iteration's write safe)
        unsigned long long kk = kbuf[(par * 2 + c) * 4 + 0];
        unsigned long long k1 = kbuf[(par * 2 + c) * 4 + 1];
        unsigned long long k2 = kbuf[(par * 2 + c) * 4 + 2];
        unsigned long long k3 = kbuf[(par * 2 + c) * 4 + 3];
        if (k1 > kk) kk = k1;
        if (k2 > kk) kk = k2;
        if (k3 > kk) kk = k3;
        int nxt = (int)(~(unsigned)kk);

        cx = px[nxt]; cy = py[nxt]; cz = pz[nxt];
        if (lt == 0) {
            sel[i * 3 + 0] = cx;
            sel[i * 3 + 1] = cy;
            sel[i * 3 + 2] = cz;
        }
    }
    __syncthreads();
    float* cp = cpos + (size_t)b * S * 3;
    for (int j = lt; j < S * 3; j += 256) cp[j] = sel[j];
}

// ---------------------------------------------------------------------------
// Radius neighbor search body (bit-exact top_k semantics), NT threads.
// Output order within the <=K set is arbitrary (downstream is max-aggregate
// over the set, order-independent); >K case is fully sorted (exact top-k).
// ---------------------------------------------------------------------------
template <int N, int NT>
__device__ __forceinline__ void radius_body(const float* __restrict__ pos,
                                            const float* __restrict__ cpos,
                                            int M, float rr,
                                            int* __restrict__ nbr,
                                            int* __restrict__ cnt,
                                            char* smem, int bm) {
    unsigned long long* list = (unsigned long long*)smem;
    int* c_sh = (int*)(smem + (size_t)N * 8);

    const int b   = bm / M;
    const int tid = threadIdx.x;
    const float* P = pos + (size_t)b * N * 3;

    const float cx = cpos[bm * 3 + 0];
    const float cy = cpos[bm * 3 + 1];
    const float cz = cpos[bm * 3 + 2];

    if (tid == 0) *c_sh = 0;
    __syncthreads();

    for (int i = tid; i < N; i += NT) {
        float d2 = dist2_exact(cx, cy, cz, P[i * 3], P[i * 3 + 1], P[i * 3 + 2]);
        if (d2 <= rr) {
            int slot = atomicAdd(c_sh, 1);
            list[slot] = ((unsigned long long)__float_as_uint(d2) << 32) | (unsigned int)i;
        }
    }
    __syncthreads();
    int C = *c_sh;

    if (C <= KNBR) {
        if (tid < C) nbr[(size_t)bm * KNBR + tid] = (int)(list[tid] & 0xffffffffu);
        if (tid == 0) cnt[bm] = C;
        return;
    }

    int P2 = 1;
    while (P2 < C) P2 <<= 1;
    for (int i = C + tid; i < P2; i += NT) list[i] = ~0ULL;
    __syncthreads();
    for (int k = 2; k <= P2; k <<= 1) {
        for (int j = k >> 1; j > 0; j >>= 1) {
            for (int i = tid; i < P2; i += NT) {
                int l = i ^ j;
                if (l > i) {
                    unsigned long long a = list[i], bb = list[l];
                    bool up = ((i & k) == 0);
                    if ((a > bb) == up) { list[i] = bb; list[l] = a; }
                }
            }
            __syncthreads();
        }
    }
    if (tid < KNBR) nbr[(size_t)bm * KNBR + tid] = (int)(list[tid] & 0xffffffffu);
    if (tid == 0) cnt[bm] = KNBR;
}

// ---------------------------------------------------------------------------
// Weight prep body: W [K][N] f32 -> Wt [N][Kpad] bf16, grid-stride.
// ---------------------------------------------------------------------------
__device__ __forceinline__ void wprep_body(const float* __restrict__ W,
                                           ushort* __restrict__ Wt,
                                           int K, int N, int Kpad, int stride) {
    const int total = N * Kpad;
    for (int e = threadIdx.x; e < total; e += stride) {
        const int n = e / Kpad, k = e - n * Kpad;
        Wt[e] = (k < K) ? f2bf(W[(size_t)k * N + n]) : (ushort)0;
    }
}

// ---------------------------------------------------------------------------
// Fused dispatch 1: blocks [0,4) = FPS stage 1 pairs (512 thr = 2 clouds x
// 4 waves); blocks [4,10) = bf16 weight transposes.
// fps1 pair smem: 3*2*2048*4 + 2*1024*3*4 + 128 = 73856 B (< 160 KB/CU).
// ---------------------------------------------------------------------------
__global__ __launch_bounds__(512) void fps1_wprep_kernel(
    const float* __restrict__ pos, float* __restrict__ cpos1,
    const float* __restrict__ W1a, ushort* __restrict__ Wt1a,
    const float* __restrict__ W1b, ushort* __restrict__ Wt1b,
    const float* __restrict__ W1c, ushort* __restrict__ Wt1c,
    const float* __restrict__ W2a, ushort* __restrict__ Wt2a,
    const float* __restrict__ W2b, ushort* __restrict__ Wt2b,
    const float* __restrict__ W2c, ushort* __restrict__ Wt2c) {
    __shared__ __align__(16) char smem[3 * 2 * NPTS * 4 + 2 * S1CNT * 3 * 4 + 128];
    const int bx = blockIdx.x;
    if (bx < B_CL / 2) { fps_pair_body<NPTS, S1CNT>(pos, cpos1, bx * 2, smem); return; }
    switch (bx - B_CL / 2) {
        case 0: wprep_body(W1a, Wt1a, 3,   64,  40,  512); break;
        case 1: wprep_body(W1b, Wt1b, 64,  64,  72,  512); break;
        case 2: wprep_body(W1c, Wt1c, 64,  128, 72,  512); break;
        case 3: wprep_body(W2a, Wt2a, 131, 128, 168, 512); break;
        case 4: wprep_body(W2b, Wt2b, 128, 128, 136, 512); break;
        case 5: wprep_body(W2c, Wt2c, 128, 256, 136, 512); break;
        default: break;
    }
}

// ---------------------------------------------------------------------------
// Fused dispatch 2 (512 thr): blocks [0, 8192) = radius stage 1; blocks
// [8192, 8196) = FPS stage 2 pairs (needs only cpos1; hides inside).
// fps2 pair smem: 3*2*1024*4 + 2*256*3*4 + 128 = 30848 B; radius needs 16400.
// ---------------------------------------------------------------------------
__global__ __launch_bounds__(512) void radius1_fps2_kernel(const float* __restrict__ pos,
                                                           const float* __restrict__ cpos1,
                                                           float rr1,
                                                           int* __restrict__ nbr1,
                                                           int* __restrict__ cnt1,
                                                           float* __restrict__ cpos2) {
    constexpr int    RB   = B_CL * S1CNT;                 // 8192 radius blocks
    constexpr size_t SM_F = 3 * 2 * S1CNT * 4 + 2 * S2CNT * 3 * 4 + 128;  // 30848
    constexpr size_t SM_R = (size_t)NPTS * 8 + 16;        // 16400
    __shared__ __align__(16) char smem[SM_F > SM_R ? SM_F : SM_R];
    if (blockIdx.x < RB)
        radius_body<NPTS, 512>(pos, cpos1, S1CNT, rr1, nbr1, cnt1, smem, blockIdx.x);
    else
        fps_pair_body<S1CNT, S2CNT>(cpos1, cpos2, (int)(blockIdx.x - RB) * 2, smem);
}

// ---------------------------------------------------------------------------
// SA1 PointNetConv via MFMA: [3 -> 64 -> 64 -> 128] per centroid, max-agg.
// ---------------------------------------------------------------------------
__device__ __forceinline__ void conv1_body(const float* __restrict__ pos,
                                           const float* __restrict__ cpos,
                                           const int* __restrict__ nbr,
                                           const int* __restrict__ cnt,
                                           const ushort* __restrict__ Wt1, const float* __restrict__ b1,
                                           const ushort* __restrict__ Wt2, const float* __restrict__ b2,
                                           const ushort* __restrict__ Wt3, const float* __restrict__ b3,
                                           ushort* __restrict__ h1,
                                           int bm, char* smem) {
    ushort* act1 = (ushort*)smem;            // [64*72]
    ushort* act2 = act1 + 64 * 72;           // [64*72]
    int*    snbr = (int*)(act2 + 64 * 72);   // [KNBR]

    const int b   = bm >> 10;            // S1CNT = 1024
    const int tid = threadIdx.x;
    const int C   = cnt[bm];

    const float cx = cpos[bm * 3 + 0];
    const float cy = cpos[bm * 3 + 1];
    const float cz = cpos[bm * 3 + 2];

    if (tid < KNBR) snbr[tid] = (tid < C) ? nbr[(size_t)bm * KNBR + tid] : 0;
    __syncthreads();

    const int lane = tid & 63, w = tid >> 6;
    const int lrow = lane & 15;          // frag row/col within 16
    const int lk8  = (lane >> 4) * 8;    // frag k-base
    const int rbase = (lane >> 4) * 4;   // C-frag row base
    const f32x4 zz = {0.f, 0.f, 0.f, 0.f};

    // ---- build A0 frags in registers (K=3, k>=3 zero; lanes with k-base>=8 zero)
    short8b a0[4];
    #pragma unroll
    for (int mt = 0; mt < 4; ++mt) {
        short8b a = {0, 0, 0, 0, 0, 0, 0, 0};
        if (lane < 16) {
            const int nb = snbr[mt * 16 + lrow];
            const float* pp = pos + ((size_t)b * NPTS + nb) * 3;
            a[0] = (short)f2bf(pp[0] - cx);
            a[1] = (short)f2bf(pp[1] - cy);
            a[2] = (short)f2bf(pp[2] - cz);
        }
        a0[mt] = a;
    }

    // ---- L1: K=3 (1 kstep), N=64 -> 1 ntile per wave
    {
        const int nt = w;
        short8b bf = ldfrag(Wt1 + (size_t)(nt * 16 + lrow) * 40 + lk8);
        const float bj = b1[nt * 16 + lrow];
        #pragma unroll
        for (int mt = 0; mt < 4; ++mt) {
            f32x4 acc = mfma16(a0[mt], bf, zz);
            #pragma unroll
            for (int r = 0; r < 4; ++r) {
                const int row = mt * 16 + rbase + r;
                act1[row * 72 + nt * 16 + lrow] = f2bf(fmaxf(acc[r] + bj, 0.f));
            }
        }
    }
    __syncthreads();

    // ---- L2: K=64 (2 ksteps), N=64 -> 1 ntile per wave
    {
        short8b af[4][2];
        #pragma unroll
        for (int mt = 0; mt < 4; ++mt)
            #pragma unroll
            for (int ks = 0; ks < 2; ++ks)
                af[mt][ks] = ldfrag(&act1[(mt * 16 + lrow) * 72 + ks * 32 + lk8]);
        const int nt = w;
        short8b bf0 = ldfrag(Wt2 + (size_t)(nt * 16 + lrow) * 72 + 0  + lk8);
        short8b bf1 = ldfrag(Wt2 + (size_t)(nt * 16 + lrow) * 72 + 32 + lk8);
        const float bj = b2[nt * 16 + lrow];
        #pragma unroll
        for (int mt = 0; mt < 4; ++mt) {
            f32x4 acc = mfma16(af[mt][0], bf0, zz);
            acc = mfma16(af[mt][1], bf1, acc);
            #pragma unroll
            for (int r = 0; r < 4; ++r) {
                const int row = mt * 16 + rbase + r;
                act2[row * 72 + nt * 16 + lrow] = f2bf(fmaxf(acc[r] + bj, 0.f));
            }
        }
    }
    __syncthreads();

    // ---- L3: K=64 (2 ksteps), N=128 -> 2 ntiles per wave; no relu; masked max
    {
        short8b af[4][2];
        #pragma unroll
        for (int mt = 0; mt < 4; ++mt)
            #pragma unroll
            for (int ks = 0; ks < 2; ++ks)
                af[mt][ks] = ldfrag(&act2[(mt * 16 + lrow) * 72 + ks * 32 + lk8]);
        #pragma unroll
        for (int nti = 0; nti < 2; ++nti) {
            const int nt = w * 2 + nti;
            short8b bf0 = ldfrag(Wt3 + (size_t)(nt * 16 + lrow) * 72 + 0  + lk8);
            short8b bf1 = ldfrag(Wt3 + (size_t)(nt * 16 + lrow) * 72 + 32 + lk8);
            const float bj = b3[nt * 16 + lrow];
            float vm = -3.4e38f;
            #pragma unroll
            for (int mt = 0; mt < 4; ++mt) {
                f32x4 acc = mfma16(af[mt][0], bf0, zz);
                acc = mfma16(af[mt][1], bf1, acc);
                #pragma unroll
                for (int r = 0; r < 4; ++r) {
                    const int m = mt * 16 + rbase + r;
                    if (m < C) vm = fmaxf(vm, acc[r] + bj);
                }
            }
            vm = fmaxf(vm, __shfl_xor(vm, 16));
            vm = fmaxf(vm, __shfl_xor(vm, 32));
            if (lane < 16) h1[(size_t)bm * 128 + nt * 16 + lrow] = f2bf(vm);
        }
    }
}

// Fused dispatch 3: blocks [0,8192) = conv1; blocks [8192,10240) = radius
// stage 2 (needs cpos1/cpos2 only, independent of conv1's h1).
__global__ __launch_bounds__(256) void conv1_rad2_kernel(
    const float* __restrict__ pos, const float* __restrict__ cpos1,
    const int* __restrict__ nbr1, const int* __restrict__ cnt1,
    const ushort* __restrict__ Wt1, const float* __restrict__ b1,
    const ushort* __restrict__ Wt2, const float* __restrict__ b2,
    const ushort* __restrict__ Wt3, const float* __restrict__ b3,
    ushort* __restrict__ h1,
    const float* __restrict__ cpos2, float rr2,
    int* __restrict__ nbr2, int* __restrict__ cnt2) {
    constexpr int    CB   = B_CL * S1CNT;                    // 8192 conv blocks
    constexpr size_t SM_C = (size_t)64 * 72 * 2 * 2 + KNBR * 4;
    constexpr size_t SM_R = (size_t)S1CNT * 8 + 16;
    __shared__ __align__(16) char smem[SM_C > SM_R ? SM_C : SM_R];
    if (blockIdx.x < CB)
        conv1_body(pos, cpos1, nbr1, cnt1, Wt1, b1, Wt2, b2, Wt3, b3, h1,
                   blockIdx.x, smem);
    else
        radius_body<S1CNT, 256>(cpos1, cpos2, S2CNT, rr2, nbr2, cnt2, smem,
                                (int)(blockIdx.x - CB));
}

// ---------------------------------------------------------------------------
// SA2 PointNetConv via MFMA: [131 -> 128 -> 128 -> 256] per centroid, max-agg.
// ---------------------------------------------------------------------------
__device__ __forceinline__ void conv2_body(const ushort* __restrict__ x,     // h1 bf16
                                           const float* __restrict__ ppos,   // cpos1
                                           const float* __restrict__ cpos,   // cpos2
                                           const int* __restrict__ nbr,
                                           const int* __restrict__ cnt,
                                           const ushort* __restrict__ Wt1, const float* __restrict__ b1,
                                           const ushort* __restrict__ Wt2, const float* __restrict__ b2,
                                           const ushort* __restrict__ Wt3, const float* __restrict__ b3,
                                           ushort* __restrict__ h2, int bm) {
    __shared__ ushort act0[64 * 168];    // also reused as act2 [64][136]
    __shared__ ushort act1[64 * 136];
    __shared__ int    snbr[KNBR];
    ushort* act2 = act0;

    const int b   = bm >> 8;             // S2CNT = 256
    const int tid = threadIdx.x;
    const int C   = cnt[bm];

    const float cx = cpos[bm * 3 + 0];
    const float cy = cpos[bm * 3 + 1];
    const float cz = cpos[bm * 3 + 2];

    if (tid < KNBR) snbr[tid] = (tid < C) ? nbr[(size_t)bm * KNBR + tid] : 0;
    __syncthreads();

    for (int e = tid; e < 1024; e += 256) {          // 64 rows x 16 chunks of 8 bf16
        const int k = e >> 4, c = (e & 15) * 8;
        short8b v = {0, 0, 0, 0, 0, 0, 0, 0};
        if (k < C) v = ldfrag(x + ((size_t)b * S1CNT + snbr[k]) * 128 + c);
        *(short8b*)&act0[k * 168 + c] = v;
    }
    if (tid < KNBR) {
        const int k = tid;
        float r0 = 0.f, r1 = 0.f, r2 = 0.f;
        if (k < C) {
            const float* pp = ppos + ((size_t)b * S1CNT + snbr[k]) * 3;
            r0 = pp[0] - cx; r1 = pp[1] - cy; r2 = pp[2] - cz;
        }
        act0[k * 168 + 128] = f2bf(r0);
        act0[k * 168 + 129] = f2bf(r1);
        act0[k * 168 + 130] = f2bf(r2);
        for (int c = 131; c < 160; ++c) act0[k * 168 + c] = 0;
    }
    __syncthreads();

    const int lane = tid & 63, w = tid >> 6;
    const int lrow = lane & 15;
    const int lk8  = (lane >> 4) * 8;
    const int rbase = (lane >> 4) * 4;
    const f32x4 zz = {0.f, 0.f, 0.f, 0.f};

    // ---- L1: K=131 (5 ksteps), N=128 -> 2 ntiles per wave
    {
        short8b af[4][5];
        #pragma unroll
        for (int mt = 0; mt < 4; ++mt)
            #pragma unroll
            for (int ks = 0; ks < 5; ++ks)
                af[mt][ks] = ldfrag(&act0[(mt * 16 + lrow) * 168 + ks * 32 + lk8]);
        #pragma unroll
        for (int nti = 0; nti < 2; ++nti) {
            const int nt = w * 2 + nti;
            f32x4 acc[4] = {zz, zz, zz, zz};
            #pragma unroll
            for (int ks = 0; ks < 5; ++ks) {
                short8b bf = ldfrag(Wt1 + (size_t)(nt * 16 + lrow) * 168 + ks * 32 + lk8);
                #pragma unroll
                for (int mt = 0; mt < 4; ++mt) acc[mt] = mfma16(af[mt][ks], bf, acc[mt]);
            }
            const float bj = b1[nt * 16 + lrow];
            #pragma unroll
            for (int mt = 0; mt < 4; ++mt)
                #pragma unroll
                for (int r = 0; r < 4; ++r) {
                    const int row = mt * 16 + rbase + r;
                    act1[row * 136 + nt * 16 + lrow] = f2bf(fmaxf(acc[mt][r] + bj, 0.f));
                }
        }
    }
    __syncthreads();

    // ---- L2: K=128 (4 ksteps), N=128 -> 2 ntiles per wave (act1 -> act2)
    {
        short8b af[4][4];
        #pragma unroll
        for (int mt = 0; mt < 4; ++mt)
            #pragma unroll
            for (int ks = 0; ks < 4; ++ks)
                af[mt][ks] = ldfrag(&act1[(mt * 16 + lrow) * 136 + ks * 32 + lk8]);
        #pragma unroll
        for (int nti = 0; nti < 2; ++nti) {
            const int nt = w * 2 + nti;
            f32x4 acc[4] = {zz, zz, zz, zz};
            #pragma unroll
            for (int ks = 0; ks < 4; ++ks) {
                short8b bf = ldfrag(Wt2 + (size_t)(nt * 16 + lrow) * 136 + ks * 32 + lk8);
                #pragma unroll
                for (int mt = 0; mt < 4; ++mt) acc[mt] = mfma16(af[mt][ks], bf, acc[mt]);
            }
            const float bj = b2[nt * 16 + lrow];
            #pragma unroll
            for (int mt = 0; mt < 4; ++mt)
                #pragma unroll
                for (int r = 0; r < 4; ++r) {
                    const int row = mt * 16 + rbase + r;
                    act2[row * 136 + nt * 16 + lrow] = f2bf(fmaxf(acc[mt][r] + bj, 0.f));
                }
        }
    }
    __syncthreads();

    // ---- L3: K=128 (4 ksteps), N=256 -> 4 ntiles per wave; no relu; masked max
    {
        short8b af[4][4];
        #pragma unroll
        for (int mt = 0; mt < 4; ++mt)
            #pragma unroll
            for (int ks = 0; ks < 4; ++ks)
                af[mt][ks] = ldfrag(&act2[(mt * 16 + lrow) * 136 + ks * 32 + lk8]);
        #pragma unroll
        for (int nti = 0; nti < 4; ++nti) {
            const int nt = w * 4 + nti;
            f32x4 acc[4] = {zz, zz, zz, zz};
            #pragma unroll
            for (int ks = 0; ks < 4; ++ks) {
                short8b bf = ldfrag(Wt3 + (size_t)(nt * 16 + lrow) * 136 + ks * 32 + lk8);
                #pragma unroll
                for (int mt = 0; mt < 4; ++mt) acc[mt] = mfma16(af[mt][ks], bf, acc[mt]);
            }
            const float bj = b3[nt * 16 + lrow];
            float vm = -3.4e38f;
            #pragma unroll
            for (int mt = 0; mt < 4; ++mt)
                #pragma unroll
                for (int r = 0; r < 4; ++r) {
                    const int m = mt * 16 + rbase + r;
                    if (m < C) vm = fmaxf(vm, acc[mt][r] + bj);
                }
            vm = fmaxf(vm, __shfl_xor(vm, 16));
            vm = fmaxf(vm, __shfl_xor(vm, 32));
            if (lane < 16) h2[(size_t)bm * 256 + nt * 16 + lrow] = f2bf(vm);
        }
    }
}

// Fused dispatch 4: blocks [0,2048) = conv2; blocks [2048,2080) = gmax init.
__global__ __launch_bounds__(256) void conv2_init_kernel(
    const ushort* __restrict__ x, const float* __restrict__ ppos,
    const float* __restrict__ cpos, const int* __restrict__ nbr,
    const int* __restrict__ cnt,
    const ushort* __restrict__ Wt1, const float* __restrict__ b1,
    const ushort* __restrict__ Wt2, const float* __restrict__ b2,
    const ushort* __restrict__ Wt3, const float* __restrict__ b3,
    ushort* __restrict__ h2, unsigned* __restrict__ gmax) {
    constexpr int CB = B_CL * S2CNT;    // 2048
    if (blockIdx.x < CB)
        conv2_body(x, ppos, cpos, nbr, cnt, Wt1, b1, Wt2, b2, Wt3, b3, h2, blockIdx.x);
    else
        gmax[(size_t)(blockIdx.x - CB) * 256 + threadIdx.x] = 0u;
}

// ---------------------------------------------------------------------------
// Global MLP [259 -> 256 -> 512 -> 1024]: 4 rows per block, VALU fp32,
// atomic-max into order-preserving-encoded uint buffer. h2 input is bf16.
// ---------------------------------------------------------------------------
__device__ __forceinline__ unsigned enc_f32(float f) {
    unsigned u = __float_as_uint(f);
    return (u & 0x80000000u) ? ~u : (u | 0x80000000u);
}

__global__ __launch_bounds__(256) void mlp3_kernel(const ushort* __restrict__ h2,
                                                   const float* __restrict__ cpos2,
                                                   const float* __restrict__ W1, const float* __restrict__ b1,
                                                   const float* __restrict__ W2, const float* __restrict__ b2,
                                                   const float* __restrict__ W3, const float* __restrict__ b3,
                                                   unsigned* __restrict__ gmax) {
    __shared__ float in4[4][260];
    __shared__ float a1s[4][256];
    __shared__ float a2s[4][512];

    const int bm0 = blockIdx.x * 4;      // first of 4 consecutive s-rows (same cloud)
    const int bcl = bm0 >> 8;            // S2CNT = 256
    const int tid = threadIdx.x;

    #pragma unroll
    for (int r = 0; r < 4; ++r) {
        in4[r][tid] = bf2f(h2[(size_t)(bm0 + r) * 256 + tid]);
        if (tid < 3) in4[r][256 + tid] = cpos2[(bm0 + r) * 3 + tid];
    }
    __syncthreads();

    {   // L1: K=259, N=256
        const float bj = b1[tid];
        float acc[4] = {bj, bj, bj, bj};
        for (int i = 0; i < 259; ++i) {
            const float w = W1[i * 256 + tid];
            #pragma unroll
            for (int r = 0; r < 4; ++r) acc[r] += in4[r][i] * w;
        }
        #pragma unroll
        for (int r = 0; r < 4; ++r) a1s[r][tid] = fmaxf(acc[r], 0.f);
    }
    __syncthreads();

    {   // L2: K=256, N=512
        const float bj0 = b2[tid], bj1 = b2[tid + 256];
        float acc0[4] = {bj0, bj0, bj0, bj0};
        float acc1[4] = {bj1, bj1, bj1, bj1};
        for (int i = 0; i < 256; ++i) {
            const float w0 = W2[i * 512 + tid];
            const float w1 = W2[i * 512 + tid + 256];
            #pragma unroll
            for (int r = 0; r < 4; ++r) {
                const float a = a1s[r][i];
                acc0[r] += a * w0;
                acc1[r] += a * w1;
            }
        }
        #pragma unroll
        for (int r = 0; r < 4; ++r) {
            a2s[r][tid]       = fmaxf(acc0[r], 0.f);
            a2s[r][tid + 256] = fmaxf(acc1[r], 0.f);
        }
    }
    __syncthreads();

    {   // L3: K=512, N=1024
        float acc[4][4];
        #pragma unroll
        for (int q = 0; q < 4; ++q) {
            const float bj = b3[tid + 256 * q];
            #pragma unroll
            for (int r = 0; r < 4; ++r) acc[q][r] = bj;
        }
        for (int i = 0; i < 512; ++i) {
            float av[4];
            #pragma unroll
            for (int r = 0; r < 4; ++r) av[r] = a2s[r][i];
            #pragma unroll
            for (int q = 0; q < 4; ++q) {
                const float w = W3[i * 1024 + 256 * q + tid];
                #pragma unroll
                for (int r = 0; r < 4; ++r) acc[q][r] += av[r] * w;
            }
        }
        #pragma unroll
        for (int q = 0; q < 4; ++q)
            #pragma unroll
            for (int r = 0; r < 4; ++r)
                atomicMax(&gmax[(size_t)bcl * 1024 + 256 * q + tid], enc_f32(acc[q][r]));
    }
}

__global__ __launch_bounds__(256) void gmax_decode_kernel(const unsigned* __restrict__ gmax,
                                                          float* __restrict__ out) {
    int t = blockIdx.x * 256 + threadIdx.x;
    unsigned u = gmax[t];
    out[t] = (u & 0x80000000u) ? __uint_as_float(u ^ 0x80000000u) : __uint_as_float(~u);
}

// ---------------------------------------------------------------------------
extern "C" void kernel_launch(void* const* d_in, const int* in_sizes, int n_in,
                              void* d_out, int out_size, void* d_ws, size_t ws_size,
                              hipStream_t stream) {
    (void)in_sizes; (void)n_in; (void)out_size; (void)ws_size;

    const float* pos = (const float*)d_in[0];
    const float* W1a = (const float*)d_in[1];  const float* b1a = (const float*)d_in[2];
    const float* W1b = (const float*)d_in[3];  const float* b1b = (const float*)d_in[4];
    const float* W1c = (const float*)d_in[5];  const float* b1c = (const float*)d_in[6];
    const float* W2a = (const float*)d_in[7];  const float* b2a = (const float*)d_in[8];
    const float* W2b = (const float*)d_in[9];  const float* b2b = (const float*)d_in[10];
    const float* W2c = (const float*)d_in[11]; const float* b2c = (const float*)d_in[12];
    const float* W3a = (const float*)d_in[13]; const float* b3a = (const float*)d_in[14];
    const float* W3b = (const float*)d_in[15]; const float* b3b = (const float*)d_in[16];
    const float* W3c = (const float*)d_in[17]; const float* b3c = (const float*)d_in[18];

    float* out = (float*)d_out;

    char* ws = (char*)d_ws;
    auto alloc = [&](size_t bytes) {
        char* p = ws;
        ws += (bytes + 255) & ~(size_t)255;
        return p;
    };
    float*    cpos1 = (float*)   alloc((size_t)B_CL * S1CNT * 3 * 4);
    int*      nbr1  = (int*)     alloc((size_t)B_CL * S1CNT * KNBR * 4);
    int*      cnt1  = (int*)     alloc((size_t)B_CL * S1CNT * 4);
    ushort*   h1    = (ushort*)  alloc((size_t)B_CL * S1CNT * 128 * 2);
    float*    cpos2 = (float*)   alloc((size_t)B_CL * S2CNT * 3 * 4);
    int*      nbr2  = (int*)     alloc((size_t)B_CL * S2CNT * KNBR * 4);
    int*      cnt2  = (int*)     alloc((size_t)B_CL * S2CNT * 4);
    ushort*   h2    = (ushort*)  alloc((size_t)B_CL * S2CNT * 256 * 2);
    unsigned* gmax  = (unsigned*)alloc((size_t)B_CL * 1024 * 4);
    ushort*   Wt1a  = (ushort*)  alloc((size_t)64  * 40  * 2);
    ushort*   Wt1b  = (ushort*)  alloc((size_t)64  * 72  * 2);
    ushort*   Wt1c  = (ushort*)  alloc((size_t)128 * 72  * 2);
    ushort*   Wt2a  = (ushort*)  alloc((size_t)128 * 168 * 2);
    ushort*   Wt2b  = (ushort*)  alloc((size_t)128 * 136 * 2);
    ushort*   Wt2c  = (ushort*)  alloc((size_t)256 * 136 * 2);

    const float RR1 = (float)(0.2 * 0.2);
    const float RR2 = (float)(0.4 * 0.4);

    // 1: FPS stage 1 (4 pair-blocks x 512 = 2 clouds each) + 6 weight-prep blocks
    fps1_wprep_kernel<<<B_CL / 2 + 6, 512, 0, stream>>>(pos, cpos1,
                                                        W1a, Wt1a, W1b, Wt1b, W1c, Wt1c,
                                                        W2a, Wt2a, W2b, Wt2b, W2c, Wt2c);
    // 2: radius stage 1 (512 thr) + FPS stage 2 pairs
    radius1_fps2_kernel<<<B_CL * S1CNT + B_CL / 2, 512, 0, stream>>>(pos, cpos1, RR1,
                                                                     nbr1, cnt1, cpos2);
    // 3: conv1 + radius stage 2
    conv1_rad2_kernel<<<B_CL * S1CNT + B_CL * S2CNT, 256, 0, stream>>>(
        pos, cpos1, nbr1, cnt1, Wt1a, b1a, Wt1b, b1b, Wt1c, b1c, h1,
        cpos2, RR2, nbr2, cnt2);
    // 4: conv2 + gmax init
    conv2_init_kernel<<<B_CL * S2CNT + (B_CL * 1024) / 256, 256, 0, stream>>>(
        h1, cpos1, cpos2, nbr2, cnt2, Wt2a, b2a, Wt2b, b2b, Wt2c, b2c, h2, gmax);
    // 5: global MLP + max pool
    mlp3_kernel<<<(B_CL * S2CNT) / 4, 256, 0, stream>>>(h2, cpos2,
                                                        W3a, b3a, W3b, b3b, W3c, b3c, gmax);
    // 6: decode
    gmax_decode_kernel<<<(B_CL * 1024) / 256, 256, 0, stream>>>(gmax, out);
}

// Round 14
// 840.381 us; speedup vs baseline: 1.1219x; 1.1219x over previous
//
#include <hip/hip_runtime.h>
#include <hip/hip_bf16.h>
#include <cstdint>
#include <cstddef>

// Problem constants (match reference)
#define B_CL   8
#define NPTS   2048
#define S1CNT  1024
#define S2CNT  256
#define KNBR   64

typedef unsigned short ushort;
typedef __attribute__((ext_vector_type(8))) short short8b;  // 8 bf16 = MFMA A/B frag
typedef __attribute__((ext_vector_type(4))) float f32x4;    // MFMA C/D frag

__device__ __forceinline__ ushort f2bf(float f) {
    union { __hip_bfloat16 h; ushort u; } v;
    v.h = __float2bfloat16(f);
    return v.u;
}
__device__ __forceinline__ float bf2f(ushort u) {
    return __uint_as_float(((unsigned)u) << 16);
}
__device__ __forceinline__ short8b ldfrag(const ushort* p) {
    return *(const short8b*)p;
}
__device__ __forceinline__ f32x4 mfma16(short8b a, short8b b, f32x4 c) {
    return __builtin_amdgcn_mfma_f32_16x16x32_bf16(a, b, c, 0, 0, 0);
}

// Exact f32 squared distance in the reference's summation order.
__device__ __forceinline__ float dist2_exact(float ax, float ay, float az,
                                             float bx, float by, float bz) {
    float dx = __fsub_rn(ax, bx);
    float dy = __fsub_rn(ay, by);
    float dz = __fsub_rn(az, bz);
    return __fadd_rn(__fadd_rn(__fmul_rn(dx, dx), __fmul_rn(dy, dy)), __fmul_rn(dz, dz));
}

// 64-lane max-reduce of a u64 key via DPP. Result valid in lane 63.
__device__ __forceinline__ unsigned long long wave_max_u64(unsigned long long k) {
#define DPP_STEP(CTRL) {                                                            \
    unsigned lo = (unsigned)k, hi = (unsigned)(k >> 32);                            \
    unsigned nlo = (unsigned)__builtin_amdgcn_update_dpp((int)lo, (int)lo, CTRL,    \
                                                         0xf, 0xf, false);          \
    unsigned nhi = (unsigned)__builtin_amdgcn_update_dpp((int)hi, (int)hi, CTRL,    \
                                                         0xf, 0xf, false);          \
    unsigned long long nk = ((unsigned long long)nhi << 32) | nlo;                  \
    if (nk > k) k = nk;                                                             \
}
    DPP_STEP(0x111);  // row_shr:1
    DPP_STEP(0x112);  // row_shr:2
    DPP_STEP(0x114);  // row_shr:4
    DPP_STEP(0x118);  // row_shr:8
    DPP_STEP(0x142);  // row_bcast:15
    DPP_STEP(0x143);  // row_bcast:31
#undef DPP_STEP
    return k;
}

// ---------------------------------------------------------------------------
// Farthest point sampling — round-7 algorithm (measured best) + speculative
// resolve: after the barrier, load ALL 4 wave keys AND all 12 candidate
// coordinates immediately (independent broadcast reads), then select the
// block winner with register-only cndmasks. This overlaps the key-compare
// chain with the coordinate-load latency, removing the dependent second LDS
// round trip (~80-150 cyc/iter) from the critical path.
// Selection is bit-exact: d2 in reference op order; key=(d2,~idx) u64-max.
// ---------------------------------------------------------------------------
template <int N, int S>
__device__ __forceinline__ void fps_body(const float* __restrict__ pos,
                                         float* __restrict__ cpos,
                                         int b, char* smem) {
    constexpr int PPT = N / 256;
    float* px  = (float*)smem;                 // [N]
    float* py  = px + N;                       // [N]
    float* pz  = py + N;                       // [N]
    float* sel = pz + N;                       // [S*3]
    unsigned long long* kbuf = (unsigned long long*)(sel + S * 3);  // [2][4]

    const int tid = threadIdx.x;
    const float* P = pos + (size_t)b * N * 3;

    float ox[PPT], oy[PPT], oz[PPT], d[PPT];
    #pragma unroll
    for (int j = 0; j < PPT; ++j) {
        int idx = tid + 256 * j;
        float x = P[idx * 3 + 0];
        float y = P[idx * 3 + 1];
        float z = P[idx * 3 + 2];
        px[idx] = x; py[idx] = y; pz[idx] = z;
        ox[j] = x; oy[j] = y; oz[j] = z;
        d[j] = 1e30f;
    }
    __syncthreads();

    float cx = px[0], cy = py[0], cz = pz[0];
    if (tid == 0) { sel[0] = cx; sel[1] = cy; sel[2] = cz; }

    for (int i = 1; i < S; ++i) {
        // update distances with current point; local argmax (strict > keeps
        // the first/min index since idx increases with j)
        float bv = -1.0f;
        int   bi = 0;
        #pragma unroll
        for (int j = 0; j < PPT; ++j) {
            int idx = tid + 256 * j;
            float dd = dist2_exact(ox[j], oy[j], oz[j], cx, cy, cz);
            float nd = fminf(d[j], dd);
            d[j] = nd;
            if (nd > bv) { bv = nd; bi = idx; }
        }
        // pack (d2, ~idx): u64 max == (max d2, then min idx). d2 >= 0 so the
        // f32 bit pattern is order-preserving.
        unsigned long long key =
            ((unsigned long long)__float_as_uint(bv) << 32) | (unsigned)(~bi);
        key = wave_max_u64(key);

        const int par = i & 1;
        if ((tid & 63) == 63) kbuf[par * 4 + (tid >> 6)] = key;
        __syncthreads();

        // speculative resolve: all key loads + all 12 candidate coord loads
        // issued up front (broadcast, conflict-free); compare chain overlaps
        // the coord-load latency; winner picked with register cndmasks.
        unsigned long long k0 = kbuf[par * 4 + 0];
        unsigned long long k1 = kbuf[par * 4 + 1];
        unsigned long long k2 = kbuf[par * 4 + 2];
        unsigned long long k3 = kbuf[par * 4 + 3];
        const int n0 = (int)(~(unsigned)k0);
        const int n1 = (int)(~(unsigned)k1);
        const int n2 = (int)(~(unsigned)k2);
        const int n3 = (int)(~(unsigned)k3);
        float X0 = px[n0], Y0 = py[n0], Z0 = pz[n0];
        float X1 = px[n1], Y1 = py[n1], Z1 = pz[n1];
        float X2 = px[n2], Y2 = py[n2], Z2 = pz[n2];
        float X3 = px[n3], Y3 = py[n3], Z3 = pz[n3];
        const bool s01 = k1 > k0;
        const unsigned long long kA = s01 ? k1 : k0;
        const float XA = s01 ? X1 : X0, YA = s01 ? Y1 : Y0, ZA = s01 ? Z1 : Z0;
        const bool s23 = k3 > k2;
        const unsigned long long kB = s23 ? k3 : k2;
        const float XB = s23 ? X3 : X2, YB = s23 ? Y3 : Y2, ZB = s23 ? Z3 : Z2;
        const bool sAB = kB > kA;
        cx = sAB ? XB : XA;
        cy = sAB ? YB : YA;
        cz = sAB ? ZB : ZA;

        if (tid == 0) {
            sel[i * 3 + 0] = cx;
            sel[i * 3 + 1] = cy;
            sel[i * 3 + 2] = cz;
        }
    }
    __syncthreads();
    float* cp = cpos + (size_t)b * S * 3;
    for (int j = tid; j < S * 3; j += 256) cp[j] = sel[j];
}

// ---------------------------------------------------------------------------
// Radius neighbor search body (bit-exact top_k semantics), smem passed in.
// 256 threads.
// ---------------------------------------------------------------------------
template <int N>
__device__ __forceinline__ void radius_body(const float* __restrict__ pos,
                                            const float* __restrict__ cpos,
                                            int M, float rr,
                                            int* __restrict__ nbr,
                                            int* __restrict__ cnt,
                                            char* smem, int bm) {
    unsigned long long* list = (unsigned long long*)smem;
    int* c_sh = (int*)(smem + (size_t)N * 8);

    const int b   = bm / M;
    const int tid = threadIdx.x;
    const float* P = pos + (size_t)b * N * 3;

    const float cx = cpos[bm * 3 + 0];
    const float cy = cpos[bm * 3 + 1];
    const float cz = cpos[bm * 3 + 2];

    if (tid == 0) *c_sh = 0;
    __syncthreads();

    for (int i = tid; i < N; i += 256) {
        float d2 = dist2_exact(cx, cy, cz, P[i * 3], P[i * 3 + 1], P[i * 3 + 2]);
        if (d2 <= rr) {
            int slot = atomicAdd(c_sh, 1);
            list[slot] = ((unsigned long long)__float_as_uint(d2) << 32) | (unsigned int)i;
        }
    }
    __syncthreads();
    int C = *c_sh;

    if (C <= KNBR) {
        if (tid < C) nbr[(size_t)bm * KNBR + tid] = (int)(list[tid] & 0xffffffffu);
        if (tid == 0) cnt[bm] = C;
        return;
    }

    int P2 = 1;
    while (P2 < C) P2 <<= 1;
    for (int i = C + tid; i < P2; i += 256) list[i] = ~0ULL;
    __syncthreads();
    for (int k = 2; k <= P2; k <<= 1) {
        for (int j = k >> 1; j > 0; j >>= 1) {
            for (int i = tid; i < P2; i += 256) {
                int l = i ^ j;
                if (l > i) {
                    unsigned long long a = list[i], bb = list[l];
                    bool up = ((i & k) == 0);
                    if ((a > bb) == up) { list[i] = bb; list[l] = a; }
                }
            }
            __syncthreads();
        }
    }
    if (tid < KNBR) nbr[(size_t)bm * KNBR + tid] = (int)(list[tid] & 0xffffffffu);
    if (tid == 0) cnt[bm] = KNBR;
}

// ---------------------------------------------------------------------------
// Weight prep body: W [K][N] f32 -> Wt [N][Kpad] bf16, grid-stride 256 thr.
// ---------------------------------------------------------------------------
__device__ __forceinline__ void wprep_body(const float* __restrict__ W,
                                           ushort* __restrict__ Wt,
                                           int K, int N, int Kpad) {
    const int total = N * Kpad;
    for (int e = threadIdx.x; e < total; e += 256) {
        const int n = e / Kpad, k = e - n * Kpad;
        Wt[e] = (k < K) ? f2bf(W[(size_t)k * N + n]) : (ushort)0;
    }
}

// ---------------------------------------------------------------------------
// Fused dispatch 1: blocks [0,8) = FPS stage 1 (256 thr); blocks [8,14) =
// bf16 weight transposes (fill idle CUs during the serial FPS).
// ---------------------------------------------------------------------------
__global__ __launch_bounds__(256) void fps1_wprep_kernel(
    const float* __restrict__ pos, float* __restrict__ cpos1,
    const float* __restrict__ W1a, ushort* __restrict__ Wt1a,
    const float* __restrict__ W1b, ushort* __restrict__ Wt1b,
    const float* __restrict__ W1c, ushort* __restrict__ Wt1c,
    const float* __restrict__ W2a, ushort* __restrict__ Wt2a,
    const float* __restrict__ W2b, ushort* __restrict__ Wt2b,
    const float* __restrict__ W2c, ushort* __restrict__ Wt2c) {
    // fps<2048,1024>: 3*2048*4 + 1024*3*4 + 64 = 36928 B
    __shared__ __align__(16) char smem[3 * NPTS * 4 + S1CNT * 3 * 4 + 64];
    const int bx = blockIdx.x;
    if (bx < B_CL) { fps_body<NPTS, S1CNT>(pos, cpos1, bx, smem); return; }
    switch (bx - B_CL) {
        case 0: wprep_body(W1a, Wt1a, 3,   64,  40);  break;
        case 1: wprep_body(W1b, Wt1b, 64,  64,  72);  break;
        case 2: wprep_body(W1c, Wt1c, 64,  128, 72);  break;
        case 3: wprep_body(W2a, Wt2a, 131, 128, 168); break;
        case 4: wprep_body(W2b, Wt2b, 128, 128, 136); break;
        case 5: wprep_body(W2c, Wt2c, 128, 256, 136); break;
        default: break;
    }
}

// ---------------------------------------------------------------------------
// Fused dispatch 2: blocks [0, 8192) = radius stage 1; blocks [8192, 8200) =
// FPS stage 2 (needs only cpos1; hides inside this dispatch).
// fps<1024,256> needs 3*1024*4 + 256*3*4 + 64 = 15424 B <= radius's 16400 B.
// ---------------------------------------------------------------------------
__global__ __launch_bounds__(256) void radius1_fps2_kernel(const float* __restrict__ pos,
                                                           const float* __restrict__ cpos1,
                                                           float rr1,
                                                           int* __restrict__ nbr1,
                                                           int* __restrict__ cnt1,
                                                           float* __restrict__ cpos2) {
    constexpr int    RB   = B_CL * S1CNT;                 // 8192 radius blocks
    constexpr size_t SM_R = (size_t)NPTS * 8 + 16;        // 16.4 KB
    __shared__ __align__(16) char smem[SM_R];
    if (blockIdx.x < RB)
        radius_body<NPTS>(pos, cpos1, S1CNT, rr1, nbr1, cnt1, smem, blockIdx.x);
    else
        fps_body<S1CNT, S2CNT>(cpos1, cpos2, (int)(blockIdx.x - RB), smem);
}

// ---------------------------------------------------------------------------
// SA1 PointNetConv via MFMA: [3 -> 64 -> 64 -> 128] per centroid, max-agg.
// ---------------------------------------------------------------------------
__device__ __forceinline__ void conv1_body(const float* __restrict__ pos,
                                           const float* __restrict__ cpos,
                                           const int* __restrict__ nbr,
                                           const int* __restrict__ cnt,
                                           const ushort* __restrict__ Wt1, const float* __restrict__ b1,
                                           const ushort* __restrict__ Wt2, const float* __restrict__ b2,
                                           const ushort* __restrict__ Wt3, const float* __restrict__ b3,
                                           ushort* __restrict__ h1,
                                           int bm, char* smem) {
    ushort* act1 = (ushort*)smem;            // [64*72]
    ushort* act2 = act1 + 64 * 72;           // [64*72]
    int*    snbr = (int*)(act2 + 64 * 72);   // [KNBR]

    const int b   = bm >> 10;            // S1CNT = 1024
    const int tid = threadIdx.x;
    const int C   = cnt[bm];

    const float cx = cpos[bm * 3 + 0];
    const float cy = cpos[bm * 3 + 1];
    const float cz = cpos[bm * 3 + 2];

    if (tid < KNBR) snbr[tid] = (tid < C) ? nbr[(size_t)bm * KNBR + tid] : 0;
    __syncthreads();

    const int lane = tid & 63, w = tid >> 6;
    const int lrow = lane & 15;          // frag row/col within 16
    const int lk8  = (lane >> 4) * 8;    // frag k-base
    const int rbase = (lane >> 4) * 4;   // C-frag row base
    const f32x4 zz = {0.f, 0.f, 0.f, 0.f};

    // ---- build A0 frags in registers (K=3, k>=3 zero; lanes with k-base>=8 zero)
    short8b a0[4];
    #pragma unroll
    for (int mt = 0; mt < 4; ++mt) {
        short8b a = {0, 0, 0, 0, 0, 0, 0, 0};
        if (lane < 16) {
            const int nb = snbr[mt * 16 + lrow];
            const float* pp = pos + ((size_t)b * NPTS + nb) * 3;
            a[0] = (short)f2bf(pp[0] - cx);
            a[1] = (short)f2bf(pp[1] - cy);
            a[2] = (short)f2bf(pp[2] - cz);
        }
        a0[mt] = a;
    }

    // ---- L1: K=3 (1 kstep), N=64 -> 1 ntile per wave
    {
        const int nt = w;
        short8b bf = ldfrag(Wt1 + (size_t)(nt * 16 + lrow) * 40 + lk8);
        const float bj = b1[nt * 16 + lrow];
        #pragma unroll
        for (int mt = 0; mt < 4; ++mt) {
            f32x4 acc = mfma16(a0[mt], bf, zz);
            #pragma unroll
            for (int r = 0; r < 4; ++r) {
                const int row = mt * 16 + rbase + r;
                act1[row * 72 + nt * 16 + lrow] = f2bf(fmaxf(acc[r] + bj, 0.f));
            }
        }
    }
    __syncthreads();

    // ---- L2: K=64 (2 ksteps), N=64 -> 1 ntile per wave
    {
        short8b af[4][2];
        #pragma unroll
        for (int mt = 0; mt < 4; ++mt)
            #pragma unroll
            for (int ks = 0; ks < 2; ++ks)
                af[mt][ks] = ldfrag(&act1[(mt * 16 + lrow) * 72 + ks * 32 + lk8]);
        const int nt = w;
        short8b bf0 = ldfrag(Wt2 + (size_t)(nt * 16 + lrow) * 72 + 0  + lk8);
        short8b bf1 = ldfrag(Wt2 + (size_t)(nt * 16 + lrow) * 72 + 32 + lk8);
        const float bj = b2[nt * 16 + lrow];
        #pragma unroll
        for (int mt = 0; mt < 4; ++mt) {
            f32x4 acc = mfma16(af[mt][0], bf0, zz);
            acc = mfma16(af[mt][1], bf1, acc);
            #pragma unroll
            for (int r = 0; r < 4; ++r) {
                const int row = mt * 16 + rbase + r;
                act2[row * 72 + nt * 16 + lrow] = f2bf(fmaxf(acc[r] + bj, 0.f));
            }
        }
    }
    __syncthreads();

    // ---- L3: K=64 (2 ksteps), N=128 -> 2 ntiles per wave; no relu; masked max
    {
        short8b af[4][2];
        #pragma unroll
        for (int mt = 0; mt < 4; ++mt)
            #pragma unroll
            for (int ks = 0; ks < 2; ++ks)
                af[mt][ks] = ldfrag(&act2[(mt * 16 + lrow) * 72 + ks * 32 + lk8]);
        #pragma unroll
        for (int nti = 0; nti < 2; ++nti) {
            const int nt = w * 2 + nti;
            short8b bf0 = ldfrag(Wt3 + (size_t)(nt * 16 + lrow) * 72 + 0  + lk8);
            short8b bf1 = ldfrag(Wt3 + (size_t)(nt * 16 + lrow) * 72 + 32 + lk8);
            const float bj = b3[nt * 16 + lrow];
            float vm = -3.4e38f;
            #pragma unroll
            for (int mt = 0; mt < 4; ++mt) {
                f32x4 acc = mfma16(af[mt][0], bf0, zz);
                acc = mfma16(af[mt][1], bf1, acc);
                #pragma unroll
                for (int r = 0; r < 4; ++r) {
                    const int m = mt * 16 + rbase + r;
                    if (m < C) vm = fmaxf(vm, acc[r] + bj);
                }
            }
            vm = fmaxf(vm, __shfl_xor(vm, 16));
            vm = fmaxf(vm, __shfl_xor(vm, 32));
            if (lane < 16) h1[(size_t)bm * 128 + nt * 16 + lrow] = f2bf(vm);
        }
    }
}

// Fused dispatch 3: blocks [0,8192) = conv1; blocks [8192,10240) = radius
// stage 2 (needs cpos1/cpos2 only, independent of conv1's h1).
__global__ __launch_bounds__(256) void conv1_rad2_kernel(
    const float* __restrict__ pos, const float* __restrict__ cpos1,
    const int* __restrict__ nbr1, const int* __restrict__ cnt1,
    const ushort* __restrict__ Wt1, const float* __restrict__ b1,
    const ushort* __restrict__ Wt2, const float* __restrict__ b2,
    const ushort* __restrict__ Wt3, const float* __restrict__ b3,
    ushort* __restrict__ h1,
    const float* __restrict__ cpos2, float rr2,
    int* __restrict__ nbr2, int* __restrict__ cnt2) {
    constexpr int    CB   = B_CL * S1CNT;                    // 8192 conv blocks
    constexpr size_t SM_C = (size_t)64 * 72 * 2 * 2 + KNBR * 4;
    constexpr size_t SM_R = (size_t)S1CNT * 8 + 16;
    __shared__ __align__(16) char smem[SM_C > SM_R ? SM_C : SM_R];
    if (blockIdx.x < CB)
        conv1_body(pos, cpos1, nbr1, cnt1, Wt1, b1, Wt2, b2, Wt3, b3, h1,
                   blockIdx.x, smem);
    else
        radius_body<S1CNT>(cpos1, cpos2, S2CNT, rr2, nbr2, cnt2, smem,
                           (int)(blockIdx.x - CB));
}

// ---------------------------------------------------------------------------
// SA2 PointNetConv via MFMA: [131 -> 128 -> 128 -> 256] per centroid, max-agg.
// ---------------------------------------------------------------------------
__device__ __forceinline__ void conv2_body(const ushort* __restrict__ x,     // h1 bf16
                                           const float* __restrict__ ppos,   // cpos1
                                           const float* __restrict__ cpos,   // cpos2
                                           const int* __restrict__ nbr,
                                           const int* __restrict__ cnt,
                                           const ushort* __restrict__ Wt1, const float* __restrict__ b1,
                                           const ushort* __restrict__ Wt2, const float* __restrict__ b2,
                                           const ushort* __restrict__ Wt3, const float* __restrict__ b3,
                                           ushort* __restrict__ h2, int bm) {
    __shared__ ushort act0[64 * 168];    // also reused as act2 [64][136]
    __shared__ ushort act1[64 * 136];
    __shared__ int    snbr[KNBR];
    ushort* act2 = act0;

    const int b   = bm >> 8;             // S2CNT = 256
    const int tid = threadIdx.x;
    const int C   = cnt[bm];

    const float cx = cpos[bm * 3 + 0];
    const float cy = cpos[bm * 3 + 1];
    const float cz = cpos[bm * 3 + 2];

    if (tid < KNBR) snbr[tid] = (tid < C) ? nbr[(size_t)bm * KNBR + tid] : 0;
    __syncthreads();

    for (int e = tid; e < 1024; e += 256) {          // 64 rows x 16 chunks of 8 bf16
        const int k = e >> 4, c = (e & 15) * 8;
        short8b v = {0, 0, 0, 0, 0, 0, 0, 0};
        if (k < C) v = ldfrag(x + ((size_t)b * S1CNT + snbr[k]) * 128 + c);
        *(short8b*)&act0[k * 168 + c] = v;
    }
    if (tid < KNBR) {
        const int k = tid;
        float r0 = 0.f, r1 = 0.f, r2 = 0.f;
        if (k < C) {
            const float* pp = ppos + ((size_t)b * S1CNT + snbr[k]) * 3;
            r0 = pp[0] - cx; r1 = pp[1] - cy; r2 = pp[2] - cz;
        }
        act0[k * 168 + 128] = f2bf(r0);
        act0[k * 168 + 129] = f2bf(r1);
        act0[k * 168 + 130] = f2bf(r2);
        for (int c = 131; c < 160; ++c) act0[k * 168 + c] = 0;
    }
    __syncthreads();

    const int lane = tid & 63, w = tid >> 6;
    const int lrow = lane & 15;
    const int lk8  = (lane >> 4) * 8;
    const int rbase = (lane >> 4) * 4;
    const f32x4 zz = {0.f, 0.f, 0.f, 0.f};

    // ---- L1: K=131 (5 ksteps), N=128 -> 2 ntiles per wave
    {
        short8b af[4][5];
        #pragma unroll
        for (int mt = 0; mt < 4; ++mt)
            #pragma unroll
            for (int ks = 0; ks < 5; ++ks)
                af[mt][ks] = ldfrag(&act0[(mt * 16 + lrow) * 168 + ks * 32 + lk8]);
        #pragma unroll
        for (int nti = 0; nti < 2; ++nti) {
            const int nt = w * 2 + nti;
            f32x4 acc[4] = {zz, zz, zz, zz};
            #pragma unroll
            for (int ks = 0; ks < 5; ++ks) {
                short8b bf = ldfrag(Wt1 + (size_t)(nt * 16 + lrow) * 168 + ks * 32 + lk8);
                #pragma unroll
                for (int mt = 0; mt < 4; ++mt) acc[mt] = mfma16(af[mt][ks], bf, acc[mt]);
            }
            const float bj = b1[nt * 16 + lrow];
            #pragma unroll
            for (int mt = 0; mt < 4; ++mt)
                #pragma unroll
                for (int r = 0; r < 4; ++r) {
                    const int row = mt * 16 + rbase + r;
                    act1[row * 136 + nt * 16 + lrow] = f2bf(fmaxf(acc[mt][r] + bj, 0.f));
                }
        }
    }
    __syncthreads();

    // ---- L2: K=128 (4 ksteps), N=128 -> 2 ntiles per wave (act1 -> act2)
    {
        short8b af[4][4];
        #pragma unroll
        for (int mt = 0; mt < 4; ++mt)
            #pragma unroll
            for (int ks = 0; ks < 4; ++ks)
                af[mt][ks] = ldfrag(&act1[(mt * 16 + lrow) * 136 + ks * 32 + lk8]);
        #pragma unroll
        for (int nti = 0; nti < 2; ++nti) {
            const int nt = w * 2 + nti;
            f32x4 acc[4] = {zz, zz, zz, zz};
            #pragma unroll
            for (int ks = 0; ks < 4; ++ks) {
                short8b bf = ldfrag(Wt2 + (size_t)(nt * 16 + lrow) * 136 + ks * 32 + lk8);
                #pragma unroll
                for (int mt = 0; mt < 4; ++mt) acc[mt] = mfma16(af[mt][ks], bf, acc[mt]);
            }
            const float bj = b2[nt * 16 + lrow];
            #pragma unroll
            for (int mt = 0; mt < 4; ++mt)
                #pragma unroll
                for (int r = 0; r < 4; ++r) {
                    const int row = mt * 16 + rbase + r;
                    act2[row * 136 + nt * 16 + lrow] = f2bf(fmaxf(acc[mt][r] + bj, 0.f));
                }
        }
    }
    __syncthreads();

    // ---- L3: K=128 (4 ksteps), N=256 -> 4 ntiles per wave; no relu; masked max
    {
        short8b af[4][4];
        #pragma unroll
        for (int mt = 0; mt < 4; ++mt)
            #pragma unroll
            for (int ks = 0; ks < 4; ++ks)
                af[mt][ks] = ldfrag(&act2[(mt * 16 + lrow) * 136 + ks * 32 + lk8]);
        #pragma unroll
        for (int nti = 0; nti < 4; ++nti) {
            const int nt = w * 4 + nti;
            f32x4 acc[4] = {zz, zz, zz, zz};
            #pragma unroll
            for (int ks = 0; ks < 4; ++ks) {
                short8b bf = ldfrag(Wt3 + (size_t)(nt * 16 + lrow) * 136 + ks * 32 + lk8);
                #pragma unroll
                for (int mt = 0; mt < 4; ++mt) acc[mt] = mfma16(af[mt][ks], bf, acc[mt]);
            }
            const float bj = b3[nt * 16 + lrow];
            float vm = -3.4e38f;
            #pragma unroll
            for (int mt = 0; mt < 4; ++mt)
                #pragma unroll
                for (int r = 0; r < 4; ++r) {
                    const int m = mt * 16 + rbase + r;
                    if (m < C) vm = fmaxf(vm, acc[mt][r] + bj);
                }
            vm = fmaxf(vm, __shfl_xor(vm, 16));
            vm = fmaxf(vm, __shfl_xor(vm, 32));
            if (lane < 16) h2[(size_t)bm * 256 + nt * 16 + lrow] = f2bf(vm);
        }
    }
}

// Fused dispatch 4: blocks [0,2048) = conv2; blocks [2048,2080) = gmax init.
__global__ __launch_bounds__(256) void conv2_init_kernel(
    const ushort* __restrict__ x, const float* __restrict__ ppos,
    const float* __restrict__ cpos, const int* __restrict__ nbr,
    const int* __restrict__ cnt,
    const ushort* __restrict__ Wt1, const float* __restrict__ b1,
    const ushort* __restrict__ Wt2, const float* __restrict__ b2,
    const ushort* __restrict__ Wt3, const float* __restrict__ b3,
    ushort* __restrict__ h2, unsigned* __restrict__ gmax) {
    constexpr int CB = B_CL * S2CNT;    // 2048
    if (blockIdx.x < CB)
        conv2_body(x, ppos, cpos, nbr, cnt, Wt1, b1, Wt2, b2, Wt3, b3, h2, blockIdx.x);
    else
        gmax[(size_t)(blockIdx.x - CB) * 256 + threadIdx.x] = 0u;
}

// ---------------------------------------------------------------------------
// Global MLP [259 -> 256 -> 512 -> 1024]: 8 rows per block (8x W reuse vs 4x:
// halves per-row W1/W2/W3 L2 traffic), VALU fp32, atomic-max into encoded
// uint buffer. h2 input is bf16.
// ---------------------------------------------------------------------------
__device__ __forceinline__ unsigned enc_f32(float f) {
    unsigned u = __float_as_uint(f);
    return (u & 0x80000000u) ? ~u : (u | 0x80000000u);
}

__global__ __launch_bounds__(256) void mlp3_kernel(const ushort* __restrict__ h2,
                                                   const float* __restrict__ cpos2,
                                                   const float* __restrict__ W1, const float* __restrict__ b1,
                                                   const float* __restrict__ W2, const float* __restrict__ b2,
                                                   const float* __restrict__ W3, const float* __restrict__ b3,
                                                   unsigned* __restrict__ gmax) {
    __shared__ float in8[8][260];
    __shared__ float a1s[8][256];
    __shared__ float a2s[8][512];

    const int bm0 = blockIdx.x * 8;      // first of 8 consecutive s-rows (same cloud)
    const int bcl = bm0 >> 8;            // S2CNT = 256
    const int tid = threadIdx.x;

    #pragma unroll
    for (int r = 0; r < 8; ++r) {
        in8[r][tid] = bf2f(h2[(size_t)(bm0 + r) * 256 + tid]);
        if (tid < 3) in8[r][256 + tid] = cpos2[(bm0 + r) * 3 + tid];
    }
    __syncthreads();

    {   // L1: K=259, N=256
        const float bj = b1[tid];
        float acc[8];
        #pragma unroll
        for (int r = 0; r < 8; ++r) acc[r] = bj;
        for (int i = 0; i < 259; ++i) {
            const float w = W1[i * 256 + tid];
            #pragma unroll
            for (int r = 0; r < 8; ++r) acc[r] += in8[r][i] * w;
        }
        #pragma unroll
        for (int r = 0; r < 8; ++r) a1s[r][tid] = fmaxf(acc[r], 0.f);
    }
    __syncthreads();

    {   // L2: K=256, N=512
        const float bj0 = b2[tid], bj1 = b2[tid + 256];
        float acc0[8], acc1[8];
        #pragma unroll
        for (int r = 0; r < 8; ++r) { acc0[r] = bj0; acc1[r] = bj1; }
        for (int i = 0; i < 256; ++i) {
            const float w0 = W2[i * 512 + tid];
            const float w1 = W2[i * 512 + tid + 256];
            #pragma unroll
            for (int r = 0; r < 8; ++r) {
                const float a = a1s[r][i];
                acc0[r] += a * w0;
                acc1[r] += a * w1;
            }
        }
        #pragma unroll
        for (int r = 0; r < 8; ++r) {
            a2s[r][tid]       = fmaxf(acc0[r], 0.f);
            a2s[r][tid + 256] = fmaxf(acc1[r], 0.f);
        }
    }
    __syncthreads();

    {   // L3: K=512, N=1024; thread owns channels tid + 256q, q=0..3
        float acc[4][8];
        #pragma unroll
        for (int q = 0; q < 4; ++q) {
            const float bj = b3[tid + 256 * q];
            #pragma unroll
            for (int r = 0; r < 8; ++r) acc[q][r] = bj;
        }
        for (int i = 0; i < 512; ++i) {
            float av[8];
            #pragma unroll
            for (int r = 0; r < 8; ++r) av[r] = a2s[r][i];
            #pragma unroll
            for (int q = 0; q < 4; ++q) {
                const float w = W3[i * 1024 + 256 * q + tid];
                #pragma unroll
                for (int r = 0; r < 8; ++r) acc[q][r] += av[r] * w;
            }
        }
        #pragma unroll
        for (int q = 0; q < 4; ++q) {
            float vm = acc[q][0];
            #pragma unroll
            for (int r = 1; r < 8; ++r) vm = fmaxf(vm, acc[q][r]);
            atomicMax(&gmax[(size_t)bcl * 1024 + 256 * q + tid], enc_f32(vm));
        }
    }
}

__global__ __launch_bounds__(256) void gmax_decode_kernel(const unsigned* __restrict__ gmax,
                                                          float* __restrict__ out) {
    int t = blockIdx.x * 256 + threadIdx.x;
    unsigned u = gmax[t];
    out[t] = (u & 0x80000000u) ? __uint_as_float(u ^ 0x80000000u) : __uint_as_float(~u);
}

// ---------------------------------------------------------------------------
extern "C" void kernel_launch(void* const* d_in, const int* in_sizes, int n_in,
                              void* d_out, int out_size, void* d_ws, size_t ws_size,
                              hipStream_t stream) {
    (void)in_sizes; (void)n_in; (void)out_size; (void)ws_size;

    const float* pos = (const float*)d_in[0];
    const float* W1a = (const float*)d_in[1];  const float* b1a = (const float*)d_in[2];
    const float* W1b = (const float*)d_in[3];  const float* b1b = (const float*)d_in[4];
    const float* W1c = (const float*)d_in[5];  const float* b1c = (const float*)d_in[6];
    const float* W2a = (const float*)d_in[7];  const float* b2a = (const float*)d_in[8];
    const float* W2b = (const float*)d_in[9];  const float* b2b = (const float*)d_in[10];
    const float* W2c = (const float*)d_in[11]; const float* b2c = (const float*)d_in[12];
    const float* W3a = (const float*)d_in[13]; const float* b3a = (const float*)d_in[14];
    const float* W3b = (const float*)d_in[15]; const float* b3b = (const float*)d_in[16];
    const float* W3c = (const float*)d_in[17]; const float* b3c = (const float*)d_in[18];

    float* out = (float*)d_out;

    char* ws = (char*)d_ws;
    auto alloc = [&](size_t bytes) {
        char* p = ws;
        ws += (bytes + 255) & ~(size_t)255;
        return p;
    };
    float*    cpos1 = (float*)   alloc((size_t)B_CL * S1CNT * 3 * 4);
    int*      nbr1  = (int*)     alloc((size_t)B_CL * S1CNT * KNBR * 4);
    int*      cnt1  = (int*)     alloc((size_t)B_CL * S1CNT * 4);
    ushort*   h1    = (ushort*)  alloc((size_t)B_CL * S1CNT * 128 * 2);
    float*    cpos2 = (float*)   alloc((size_t)B_CL * S2CNT * 3 * 4);
    int*      nbr2  = (int*)     alloc((size_t)B_CL * S2CNT * KNBR * 4);
    int*      cnt2  = (int*)     alloc((size_t)B_CL * S2CNT * 4);
    ushort*   h2    = (ushort*)  alloc((size_t)B_CL * S2CNT * 256 * 2);
    unsigned* gmax  = (unsigned*)alloc((size_t)B_CL * 1024 * 4);
    ushort*   Wt1a  = (ushort*)  alloc((size_t)64  * 40  * 2);
    ushort*   Wt1b  = (ushort*)  alloc((size_t)64  * 72  * 2);
    ushort*   Wt1c  = (ushort*)  alloc((size_t)128 * 72  * 2);
    ushort*   Wt2a  = (ushort*)  alloc((size_t)128 * 168 * 2);
    ushort*   Wt2b  = (ushort*)  alloc((size_t)128 * 136 * 2);
    ushort*   Wt2c  = (ushort*)  alloc((size_t)256 * 136 * 2);

    const float RR1 = (float)(0.2 * 0.2);
    const float RR2 = (float)(0.4 * 0.4);

    // 1: FPS stage 1 (8 blocks x 256, prefetch-resolve body) + 6 weight-prep blocks
    fps1_wprep_kernel<<<B_CL + 6, 256, 0, stream>>>(pos, cpos1,
                                                    W1a, Wt1a, W1b, Wt1b, W1c, Wt1c,
                                                    W2a, Wt2a, W2b, Wt2b, W2c, Wt2c);
    // 2: radius stage 1 + FPS stage 2
    radius1_fps2_kernel<<<B_CL * S1CNT + B_CL, 256, 0, stream>>>(pos, cpos1, RR1,
                                                                 nbr1, cnt1, cpos2);
    // 3: conv1 + radius stage 2
    conv1_rad2_kernel<<<B_CL * S1CNT + B_CL * S2CNT, 256, 0, stream>>>(
        pos, cpos1, nbr1, cnt1, Wt1a, b1a, Wt1b, b1b, Wt1c, b1c, h1,
        cpos2, RR2, nbr2, cnt2);
    // 4: conv2 + gmax init
    conv2_init_kernel<<<B_CL * S2CNT + (B_CL * 1024) / 256, 256, 0, stream>>>(
        h1, cpos1, cpos2, nbr2, cnt2, Wt2a, b2a, Wt2b, b2b, Wt2c, b2c, h2, gmax);
    // 5: global MLP + max pool (8 rows/block)
    mlp3_kernel<<<(B_CL * S2CNT) / 8, 256, 0, stream>>>(h2, cpos2,
                                                        W3a, b3a, W3b, b3b, W3c, b3c, gmax);
    // 6: decode
    gmax_decode_kernel<<<(B_CL * 1024) / 256, 256, 0, stream>>>(gmax, out);
}

// Round 15
// 746.049 us; speedup vs baseline: 1.2638x; 1.1264x over previous
//
#include <hip/hip_runtime.h>
#include <hip/hip_bf16.h>
#include <cstdint>
#include <cstddef>

// Problem constants (match reference)
#define B_CL   8
#define NPTS   2048
#define S1CNT  1024
#define S2CNT  256
#define KNBR   64

typedef unsigned short ushort;
typedef __attribute__((ext_vector_type(8))) short short8b;  // 8 bf16 = MFMA A/B frag
typedef __attribute__((ext_vector_type(4))) float f32x4;    // MFMA C/D frag

__device__ __forceinline__ ushort f2bf(float f) {
    union { __hip_bfloat16 h; ushort u; } v;
    v.h = __float2bfloat16(f);
    return v.u;
}
__device__ __forceinline__ float bf2f(ushort u) {
    return __uint_as_float(((unsigned)u) << 16);
}
__device__ __forceinline__ short8b ldfrag(const ushort* p) {
    return *(const short8b*)p;
}
__device__ __forceinline__ f32x4 mfma16(short8b a, short8b b, f32x4 c) {
    return __builtin_amdgcn_mfma_f32_16x16x32_bf16(a, b, c, 0, 0, 0);
}

// Exact f32 squared distance in the reference's summation order.
__device__ __forceinline__ float dist2_exact(float ax, float ay, float az,
                                             float bx, float by, float bz) {
    float dx = __fsub_rn(ax, bx);
    float dy = __fsub_rn(ay, by);
    float dz = __fsub_rn(az, bz);
    return __fadd_rn(__fadd_rn(__fmul_rn(dx, dx), __fmul_rn(dy, dy)), __fmul_rn(dz, dz));
}

// 64-lane max-reduce of a u64 key via DPP. Result valid in lane 63.
__device__ __forceinline__ unsigned long long wave_max_u64(unsigned long long k) {
#define DPP_STEP(CTRL) {                                                            \
    unsigned lo = (unsigned)k, hi = (unsigned)(k >> 32);                            \
    unsigned nlo = (unsigned)__builtin_amdgcn_update_dpp((int)lo, (int)lo, CTRL,    \
                                                         0xf, 0xf, false);          \
    unsigned nhi = (unsigned)__builtin_amdgcn_update_dpp((int)hi, (int)hi, CTRL,    \
                                                         0xf, 0xf, false);          \
    unsigned long long nk = ((unsigned long long)nhi << 32) | nlo;                  \
    if (nk > k) k = nk;                                                             \
}
    DPP_STEP(0x111);  // row_shr:1
    DPP_STEP(0x112);  // row_shr:2
    DPP_STEP(0x114);  // row_shr:4
    DPP_STEP(0x118);  // row_shr:8
    DPP_STEP(0x142);  // row_bcast:15
    DPP_STEP(0x143);  // row_bcast:31
#undef DPP_STEP
    return k;
}

// ---------------------------------------------------------------------------
// Farthest point sampling — EXACT round-7 algorithm (measured best: 461 us
// for N=2048,S=1024; beat 6 restructuring attempts in r8-r14), as a body fn.
// One cloud per block, 256 threads. Points staged in LDS (px/py/pz); selected
// coords accumulate in LDS sel[] (dumped at the end: NO global stores in the
// loop, so the single __syncthreads never waits on vmem). Per iteration:
// update+local argmax -> u64 DPP wave max -> lane63 writes parity kbuf ->
// syncthreads -> all threads resolve 4 keys, read px[nxt] (broadcast).
// Selection is bit-exact: d2 in reference op order; key=(d2,~idx) u64-max.
// ---------------------------------------------------------------------------
template <int N, int S>
__device__ __forceinline__ void fps_body(const float* __restrict__ pos,
                                         float* __restrict__ cpos,
                                         int b, char* smem) {
    constexpr int PPT = N / 256;
    float* px  = (float*)smem;                 // [N]
    float* py  = px + N;                       // [N]
    float* pz  = py + N;                       // [N]
    float* sel = pz + N;                       // [S*3]
    unsigned long long* kbuf = (unsigned long long*)(sel + S * 3);  // [2][4]

    const int tid = threadIdx.x;
    const float* P = pos + (size_t)b * N * 3;

    float ox[PPT], oy[PPT], oz[PPT], d[PPT];
    #pragma unroll
    for (int j = 0; j < PPT; ++j) {
        int idx = tid + 256 * j;
        float x = P[idx * 3 + 0];
        float y = P[idx * 3 + 1];
        float z = P[idx * 3 + 2];
        px[idx] = x; py[idx] = y; pz[idx] = z;
        ox[j] = x; oy[j] = y; oz[j] = z;
        d[j] = 1e30f;
    }
    __syncthreads();

    float cx = px[0], cy = py[0], cz = pz[0];
    if (tid == 0) { sel[0] = cx; sel[1] = cy; sel[2] = cz; }

    for (int i = 1; i < S; ++i) {
        // update distances with current point; local argmax (strict > keeps
        // the first/min index since idx increases with j)
        float bv = -1.0f;
        int   bi = 0;
        #pragma unroll
        for (int j = 0; j < PPT; ++j) {
            int idx = tid + 256 * j;
            float dd = dist2_exact(ox[j], oy[j], oz[j], cx, cy, cz);
            float nd = fminf(d[j], dd);
            d[j] = nd;
            if (nd > bv) { bv = nd; bi = idx; }
        }
        // pack (d2, ~idx): u64 max == (max d2, then min idx). d2 >= 0 so the
        // f32 bit pattern is order-preserving.
        unsigned long long key =
            ((unsigned long long)__float_as_uint(bv) << 32) | (unsigned)(~bi);
        key = wave_max_u64(key);

        const int par = i & 1;
        if ((tid & 63) == 63) kbuf[par * 4 + (tid >> 6)] = key;
        __syncthreads();

        // every thread resolves the block winner redundantly (no 2nd barrier;
        // parity double-buffer makes next iteration's overwrite safe)
        unsigned long long kk = kbuf[par * 4 + 0];
        unsigned long long k1 = kbuf[par * 4 + 1];
        unsigned long long k2 = kbuf[par * 4 + 2];
        unsigned long long k3 = kbuf[par * 4 + 3];
        if (k1 > kk) kk = k1;
        if (k2 > kk) kk = k2;
        if (k3 > kk) kk = k3;
        int nxt = (int)(~(unsigned)kk);

        cx = px[nxt]; cy = py[nxt]; cz = pz[nxt];
        if (tid == 0) {
            sel[i * 3 + 0] = cx;
            sel[i * 3 + 1] = cy;
            sel[i * 3 + 2] = cz;
        }
    }
    __syncthreads();
    float* cp = cpos + (size_t)b * S * 3;
    for (int j = tid; j < S * 3; j += 256) cp[j] = sel[j];
}

// ---------------------------------------------------------------------------
// Radius neighbor search body (bit-exact top_k semantics), smem passed in.
// 256 threads.
// ---------------------------------------------------------------------------
template <int N>
__device__ __forceinline__ void radius_body(const float* __restrict__ pos,
                                            const float* __restrict__ cpos,
                                            int M, float rr,
                                            int* __restrict__ nbr,
                                            int* __restrict__ cnt,
                                            char* smem, int bm) {
    unsigned long long* list = (unsigned long long*)smem;
    int* c_sh = (int*)(smem + (size_t)N * 8);

    const int b   = bm / M;
    const int tid = threadIdx.x;
    const float* P = pos + (size_t)b * N * 3;

    const float cx = cpos[bm * 3 + 0];
    const float cy = cpos[bm * 3 + 1];
    const float cz = cpos[bm * 3 + 2];

    if (tid == 0) *c_sh = 0;
    __syncthreads();

    for (int i = tid; i < N; i += 256) {
        float d2 = dist2_exact(cx, cy, cz, P[i * 3], P[i * 3 + 1], P[i * 3 + 2]);
        if (d2 <= rr) {
            int slot = atomicAdd(c_sh, 1);
            list[slot] = ((unsigned long long)__float_as_uint(d2) << 32) | (unsigned int)i;
        }
    }
    __syncthreads();
    int C = *c_sh;

    if (C <= KNBR) {
        if (tid < C) nbr[(size_t)bm * KNBR + tid] = (int)(list[tid] & 0xffffffffu);
        if (tid == 0) cnt[bm] = C;
        return;
    }

    int P2 = 1;
    while (P2 < C) P2 <<= 1;
    for (int i = C + tid; i < P2; i += 256) list[i] = ~0ULL;
    __syncthreads();
    for (int k = 2; k <= P2; k <<= 1) {
        for (int j = k >> 1; j > 0; j >>= 1) {
            for (int i = tid; i < P2; i += 256) {
                int l = i ^ j;
                if (l > i) {
                    unsigned long long a = list[i], bb = list[l];
                    bool up = ((i & k) == 0);
                    if ((a > bb) == up) { list[i] = bb; list[l] = a; }
                }
            }
            __syncthreads();
        }
    }
    if (tid < KNBR) nbr[(size_t)bm * KNBR + tid] = (int)(list[tid] & 0xffffffffu);
    if (tid == 0) cnt[bm] = KNBR;
}

// ---------------------------------------------------------------------------
// Weight prep body: W [K][N] f32 -> Wt [N][Kpad] bf16, grid-stride 256 thr.
// ---------------------------------------------------------------------------
__device__ __forceinline__ void wprep_body(const float* __restrict__ W,
                                           ushort* __restrict__ Wt,
                                           int K, int N, int Kpad) {
    const int total = N * Kpad;
    for (int e = threadIdx.x; e < total; e += 256) {
        const int n = e / Kpad, k = e - n * Kpad;
        Wt[e] = (k < K) ? f2bf(W[(size_t)k * N + n]) : (ushort)0;
    }
}

// ---------------------------------------------------------------------------
// Fused dispatch 1: blocks [0,8) = FPS stage 1 (256 thr, r7 body); blocks
// [8,14) = bf16 weight transposes (fill idle CUs during the serial FPS).
// ---------------------------------------------------------------------------
__global__ __launch_bounds__(256) void fps1_wprep_kernel(
    const float* __restrict__ pos, float* __restrict__ cpos1,
    const float* __restrict__ W1a, ushort* __restrict__ Wt1a,
    const float* __restrict__ W1b, ushort* __restrict__ Wt1b,
    const float* __restrict__ W1c, ushort* __restrict__ Wt1c,
    const float* __restrict__ W2a, ushort* __restrict__ Wt2a,
    const float* __restrict__ W2b, ushort* __restrict__ Wt2b,
    const float* __restrict__ W2c, ushort* __restrict__ Wt2c) {
    // fps<2048,1024>: 3*2048*4 + 1024*3*4 + 64 = 36928 B
    __shared__ __align__(16) char smem[3 * NPTS * 4 + S1CNT * 3 * 4 + 64];
    const int bx = blockIdx.x;
    if (bx < B_CL) { fps_body<NPTS, S1CNT>(pos, cpos1, bx, smem); return; }
    switch (bx - B_CL) {
        case 0: wprep_body(W1a, Wt1a, 3,   64,  40);  break;
        case 1: wprep_body(W1b, Wt1b, 64,  64,  72);  break;
        case 2: wprep_body(W1c, Wt1c, 64,  128, 72);  break;
        case 3: wprep_body(W2a, Wt2a, 131, 128, 168); break;
        case 4: wprep_body(W2b, Wt2b, 128, 128, 136); break;
        case 5: wprep_body(W2c, Wt2c, 128, 256, 136); break;
        default: break;
    }
}

// ---------------------------------------------------------------------------
// Fused dispatch 2: blocks [0, 8192) = radius stage 1; blocks [8192, 8200) =
// FPS stage 2 (needs only cpos1; hides inside this dispatch).
// fps<1024,256> needs 3*1024*4 + 256*3*4 + 64 = 15424 B <= radius's 16400 B.
// ---------------------------------------------------------------------------
__global__ __launch_bounds__(256) void radius1_fps2_kernel(const float* __restrict__ pos,
                                                           const float* __restrict__ cpos1,
                                                           float rr1,
                                                           int* __restrict__ nbr1,
                                                           int* __restrict__ cnt1,
                                                           float* __restrict__ cpos2) {
    constexpr int    RB   = B_CL * S1CNT;                 // 8192 radius blocks
    constexpr size_t SM_R = (size_t)NPTS * 8 + 16;        // 16.4 KB
    __shared__ __align__(16) char smem[SM_R];
    if (blockIdx.x < RB)
        radius_body<NPTS>(pos, cpos1, S1CNT, rr1, nbr1, cnt1, smem, blockIdx.x);
    else
        fps_body<S1CNT, S2CNT>(cpos1, cpos2, (int)(blockIdx.x - RB), smem);
}

// ---------------------------------------------------------------------------
// SA1 PointNetConv via MFMA: [3 -> 64 -> 64 -> 128] per centroid, max-agg.
// ---------------------------------------------------------------------------
__device__ __forceinline__ void conv1_body(const float* __restrict__ pos,
                                           const float* __restrict__ cpos,
                                           const int* __restrict__ nbr,
                                           const int* __restrict__ cnt,
                                           const ushort* __restrict__ Wt1, const float* __restrict__ b1,
                                           const ushort* __restrict__ Wt2, const float* __restrict__ b2,
                                           const ushort* __restrict__ Wt3, const float* __restrict__ b3,
                                           ushort* __restrict__ h1,
                                           int bm, char* smem) {
    ushort* act1 = (ushort*)smem;            // [64*72]
    ushort* act2 = act1 + 64 * 72;           // [64*72]
    int*    snbr = (int*)(act2 + 64 * 72);   // [KNBR]

    const int b   = bm >> 10;            // S1CNT = 1024
    const int tid = threadIdx.x;
    const int C   = cnt[bm];

    const float cx = cpos[bm * 3 + 0];
    const float cy = cpos[bm * 3 + 1];
    const float cz = cpos[bm * 3 + 2];

    if (tid < KNBR) snbr[tid] = (tid < C) ? nbr[(size_t)bm * KNBR + tid] : 0;
    __syncthreads();

    const int lane = tid & 63, w = tid >> 6;
    const int lrow = lane & 15;          // frag row/col within 16
    const int lk8  = (lane >> 4) * 8;    // frag k-base
    const int rbase = (lane >> 4) * 4;   // C-frag row base
    const f32x4 zz = {0.f, 0.f, 0.f, 0.f};

    // ---- build A0 frags in registers (K=3, k>=3 zero; lanes with k-base>=8 zero)
    short8b a0[4];
    #pragma unroll
    for (int mt = 0; mt < 4; ++mt) {
        short8b a = {0, 0, 0, 0, 0, 0, 0, 0};
        if (lane < 16) {
            const int nb = snbr[mt * 16 + lrow];
            const float* pp = pos + ((size_t)b * NPTS + nb) * 3;
            a[0] = (short)f2bf(pp[0] - cx);
            a[1] = (short)f2bf(pp[1] - cy);
            a[2] = (short)f2bf(pp[2] - cz);
        }
        a0[mt] = a;
    }

    // ---- L1: K=3 (1 kstep), N=64 -> 1 ntile per wave
    {
        const int nt = w;
        short8b bf = ldfrag(Wt1 + (size_t)(nt * 16 + lrow) * 40 + lk8);
        const float bj = b1[nt * 16 + lrow];
        #pragma unroll
        for (int mt = 0; mt < 4; ++mt) {
            f32x4 acc = mfma16(a0[mt], bf, zz);
            #pragma unroll
            for (int r = 0; r < 4; ++r) {
                const int row = mt * 16 + rbase + r;
                act1[row * 72 + nt * 16 + lrow] = f2bf(fmaxf(acc[r] + bj, 0.f));
            }
        }
    }
    __syncthreads();

    // ---- L2: K=64 (2 ksteps), N=64 -> 1 ntile per wave
    {
        short8b af[4][2];
        #pragma unroll
        for (int mt = 0; mt < 4; ++mt)
            #pragma unroll
            for (int ks = 0; ks < 2; ++ks)
                af[mt][ks] = ldfrag(&act1[(mt * 16 + lrow) * 72 + ks * 32 + lk8]);
        const int nt = w;
        short8b bf0 = ldfrag(Wt2 + (size_t)(nt * 16 + lrow) * 72 + 0  + lk8);
        short8b bf1 = ldfrag(Wt2 + (size_t)(nt * 16 + lrow) * 72 + 32 + lk8);
        const float bj = b2[nt * 16 + lrow];
        #pragma unroll
        for (int mt = 0; mt < 4; ++mt) {
            f32x4 acc = mfma16(af[mt][0], bf0, zz);
            acc = mfma16(af[mt][1], bf1, acc);
            #pragma unroll
            for (int r = 0; r < 4; ++r) {
                const int row = mt * 16 + rbase + r;
                act2[row * 72 + nt * 16 + lrow] = f2bf(fmaxf(acc[r] + bj, 0.f));
            }
        }
    }
    __syncthreads();

    // ---- L3: K=64 (2 ksteps), N=128 -> 2 ntiles per wave; no relu; masked max
    {
        short8b af[4][2];
        #pragma unroll
        for (int mt = 0; mt < 4; ++mt)
            #pragma unroll
            for (int ks = 0; ks < 2; ++ks)
                af[mt][ks] = ldfrag(&act2[(mt * 16 + lrow) * 72 + ks * 32 + lk8]);
        #pragma unroll
        for (int nti = 0; nti < 2; ++nti) {
            const int nt = w * 2 + nti;
            short8b bf0 = ldfrag(Wt3 + (size_t)(nt * 16 + lrow) * 72 + 0  + lk8);
            short8b bf1 = ldfrag(Wt3 + (size_t)(nt * 16 + lrow) * 72 + 32 + lk8);
            const float bj = b3[nt * 16 + lrow];
            float vm = -3.4e38f;
            #pragma unroll
            for (int mt = 0; mt < 4; ++mt) {
                f32x4 acc = mfma16(af[mt][0], bf0, zz);
                acc = mfma16(af[mt][1], bf1, acc);
                #pragma unroll
                for (int r = 0; r < 4; ++r) {
                    const int m = mt * 16 + rbase + r;
                    if (m < C) vm = fmaxf(vm, acc[r] + bj);
                }
            }
            vm = fmaxf(vm, __shfl_xor(vm, 16));
            vm = fmaxf(vm, __shfl_xor(vm, 32));
            if (lane < 16) h1[(size_t)bm * 128 + nt * 16 + lrow] = f2bf(vm);
        }
    }
}

// Fused dispatch 3: blocks [0,8192) = conv1; blocks [8192,10240) = radius
// stage 2 (needs cpos1/cpos2 only, independent of conv1's h1).
__global__ __launch_bounds__(256) void conv1_rad2_kernel(
    const float* __restrict__ pos, const float* __restrict__ cpos1,
    const int* __restrict__ nbr1, const int* __restrict__ cnt1,
    const ushort* __restrict__ Wt1, const float* __restrict__ b1,
    const ushort* __restrict__ Wt2, const float* __restrict__ b2,
    const ushort* __restrict__ Wt3, const float* __restrict__ b3,
    ushort* __restrict__ h1,
    const float* __restrict__ cpos2, float rr2,
    int* __restrict__ nbr2, int* __restrict__ cnt2) {
    constexpr int    CB   = B_CL * S1CNT;                    // 8192 conv blocks
    constexpr size_t SM_C = (size_t)64 * 72 * 2 * 2 + KNBR * 4;
    constexpr size_t SM_R = (size_t)S1CNT * 8 + 16;
    __shared__ __align__(16) char smem[SM_C > SM_R ? SM_C : SM_R];
    if (blockIdx.x < CB)
        conv1_body(pos, cpos1, nbr1, cnt1, Wt1, b1, Wt2, b2, Wt3, b3, h1,
                   blockIdx.x, smem);
    else
        radius_body<S1CNT>(cpos1, cpos2, S2CNT, rr2, nbr2, cnt2, smem,
                           (int)(blockIdx.x - CB));
}

// ---------------------------------------------------------------------------
// SA2 PointNetConv via MFMA: [131 -> 128 -> 128 -> 256] per centroid, max-agg.
// ---------------------------------------------------------------------------
__device__ __forceinline__ void conv2_body(const ushort* __restrict__ x,     // h1 bf16
                                           const float* __restrict__ ppos,   // cpos1
                                           const float* __restrict__ cpos,   // cpos2
                                           const int* __restrict__ nbr,
                                           const int* __restrict__ cnt,
                                           const ushort* __restrict__ Wt1, const float* __restrict__ b1,
                                           const ushort* __restrict__ Wt2, const float* __restrict__ b2,
                                           const ushort* __restrict__ Wt3, const float* __restrict__ b3,
                                           ushort* __restrict__ h2, int bm) {
    __shared__ ushort act0[64 * 168];    // also reused as act2 [64][136]
    __shared__ ushort act1[64 * 136];
    __shared__ int    snbr[KNBR];
    ushort* act2 = act0;

    const int b   = bm >> 8;             // S2CNT = 256
    const int tid = threadIdx.x;
    const int C   = cnt[bm];

    const float cx = cpos[bm * 3 + 0];
    const float cy = cpos[bm * 3 + 1];
    const float cz = cpos[bm * 3 + 2];

    if (tid < KNBR) snbr[tid] = (tid < C) ? nbr[(size_t)bm * KNBR + tid] : 0;
    __syncthreads();

    for (int e = tid; e < 1024; e += 256) {          // 64 rows x 16 chunks of 8 bf16
        const int k = e >> 4, c = (e & 15) * 8;
        short8b v = {0, 0, 0, 0, 0, 0, 0, 0};
        if (k < C) v = ldfrag(x + ((size_t)b * S1CNT + snbr[k]) * 128 + c);
        *(short8b*)&act0[k * 168 + c] = v;
    }
    if (tid < KNBR) {
        const int k = tid;
        float r0 = 0.f, r1 = 0.f, r2 = 0.f;
        if (k < C) {
            const float* pp = ppos + ((size_t)b * S1CNT + snbr[k]) * 3;
            r0 = pp[0] - cx; r1 = pp[1] - cy; r2 = pp[2] - cz;
        }
        act0[k * 168 + 128] = f2bf(r0);
        act0[k * 168 + 129] = f2bf(r1);
        act0[k * 168 + 130] = f2bf(r2);
        for (int c = 131; c < 160; ++c) act0[k * 168 + c] = 0;
    }
    __syncthreads();

    const int lane = tid & 63, w = tid >> 6;
    const int lrow = lane & 15;
    const int lk8  = (lane >> 4) * 8;
    const int rbase = (lane >> 4) * 4;
    const f32x4 zz = {0.f, 0.f, 0.f, 0.f};

    // ---- L1: K=131 (5 ksteps), N=128 -> 2 ntiles per wave
    {
        short8b af[4][5];
        #pragma unroll
        for (int mt = 0; mt < 4; ++mt)
            #pragma unroll
            for (int ks = 0; ks < 5; ++ks)
                af[mt][ks] = ldfrag(&act0[(mt * 16 + lrow) * 168 + ks * 32 + lk8]);
        #pragma unroll
        for (int nti = 0; nti < 2; ++nti) {
            const int nt = w * 2 + nti;
            f32x4 acc[4] = {zz, zz, zz, zz};
            #pragma unroll
            for (int ks = 0; ks < 5; ++ks) {
                short8b bf = ldfrag(Wt1 + (size_t)(nt * 16 + lrow) * 168 + ks * 32 + lk8);
                #pragma unroll
                for (int mt = 0; mt < 4; ++mt) acc[mt] = mfma16(af[mt][ks], bf, acc[mt]);
            }
            const float bj = b1[nt * 16 + lrow];
            #pragma unroll
            for (int mt = 0; mt < 4; ++mt)
                #pragma unroll
                for (int r = 0; r < 4; ++r) {
                    const int row = mt * 16 + rbase + r;
                    act1[row * 136 + nt * 16 + lrow] = f2bf(fmaxf(acc[mt][r] + bj, 0.f));
                }
        }
    }
    __syncthreads();

    // ---- L2: K=128 (4 ksteps), N=128 -> 2 ntiles per wave (act1 -> act2)
    {
        short8b af[4][4];
        #pragma unroll
        for (int mt = 0; mt < 4; ++mt)
            #pragma unroll
            for (int ks = 0; ks < 4; ++ks)
                af[mt][ks] = ldfrag(&act1[(mt * 16 + lrow) * 136 + ks * 32 + lk8]);
        #pragma unroll
        for (int nti = 0; nti < 2; ++nti) {
            const int nt = w * 2 + nti;
            f32x4 acc[4] = {zz, zz, zz, zz};
            #pragma unroll
            for (int ks = 0; ks < 4; ++ks) {
                short8b bf = ldfrag(Wt2 + (size_t)(nt * 16 + lrow) * 136 + ks * 32 + lk8);
                #pragma unroll
                for (int mt = 0; mt < 4; ++mt) acc[mt] = mfma16(af[mt][ks], bf, acc[mt]);
            }
            const float bj = b2[nt * 16 + lrow];
            #pragma unroll
            for (int mt = 0; mt < 4; ++mt)
                #pragma unroll
                for (int r = 0; r < 4; ++r) {
                    const int row = mt * 16 + rbase + r;
                    act2[row * 136 + nt * 16 + lrow] = f2bf(fmaxf(acc[mt][r] + bj, 0.f));
                }
        }
    }
    __syncthreads();

    // ---- L3: K=128 (4 ksteps), N=256 -> 4 ntiles per wave; no relu; masked max
    {
        short8b af[4][4];
        #pragma unroll
        for (int mt = 0; mt < 4; ++mt)
            #pragma unroll
            for (int ks = 0; ks < 4; ++ks)
                af[mt][ks] = ldfrag(&act2[(mt * 16 + lrow) * 136 + ks * 32 + lk8]);
        #pragma unroll
        for (int nti = 0; nti < 4; ++nti) {
            const int nt = w * 4 + nti;
            f32x4 acc[4] = {zz, zz, zz, zz};
            #pragma unroll
            for (int ks = 0; ks < 4; ++ks) {
                short8b bf = ldfrag(Wt3 + (size_t)(nt * 16 + lrow) * 136 + ks * 32 + lk8);
                #pragma unroll
                for (int mt = 0; mt < 4; ++mt) acc[mt] = mfma16(af[mt][ks], bf, acc[mt]);
            }
            const float bj = b3[nt * 16 + lrow];
            float vm = -3.4e38f;
            #pragma unroll
            for (int mt = 0; mt < 4; ++mt)
                #pragma unroll
                for (int r = 0; r < 4; ++r) {
                    const int m = mt * 16 + rbase + r;
                    if (m < C) vm = fmaxf(vm, acc[mt][r] + bj);
                }
            vm = fmaxf(vm, __shfl_xor(vm, 16));
            vm = fmaxf(vm, __shfl_xor(vm, 32));
            if (lane < 16) h2[(size_t)bm * 256 + nt * 16 + lrow] = f2bf(vm);
        }
    }
}

// Fused dispatch 4: blocks [0,2048) = conv2; blocks [2048,2080) = gmax init.
__global__ __launch_bounds__(256) void conv2_init_kernel(
    const ushort* __restrict__ x, const float* __restrict__ ppos,
    const float* __restrict__ cpos, const int* __restrict__ nbr,
    const int* __restrict__ cnt,
    const ushort* __restrict__ Wt1, const float* __restrict__ b1,
    const ushort* __restrict__ Wt2, const float* __restrict__ b2,
    const ushort* __restrict__ Wt3, const float* __restrict__ b3,
    ushort* __restrict__ h2, unsigned* __restrict__ gmax) {
    constexpr int CB = B_CL * S2CNT;    // 2048
    if (blockIdx.x < CB)
        conv2_body(x, ppos, cpos, nbr, cnt, Wt1, b1, Wt2, b2, Wt3, b3, h2, blockIdx.x);
    else
        gmax[(size_t)(blockIdx.x - CB) * 256 + threadIdx.x] = 0u;
}

// ---------------------------------------------------------------------------
// Global MLP [259 -> 256 -> 512 -> 1024]: 4 rows per block, VALU fp32,
// atomic-max into order-preserving-encoded uint buffer. h2 input is bf16.
// ---------------------------------------------------------------------------
__device__ __forceinline__ unsigned enc_f32(float f) {
    unsigned u = __float_as_uint(f);
    return (u & 0x80000000u) ? ~u : (u | 0x80000000u);
}

__global__ __launch_bounds__(256) void mlp3_kernel(const ushort* __restrict__ h2,
                                                   const float* __restrict__ cpos2,
                                                   const float* __restrict__ W1, const float* __restrict__ b1,
                                                   const float* __restrict__ W2, const float* __restrict__ b2,
                                                   const float* __restrict__ W3, const float* __restrict__ b3,
                                                   unsigned* __restrict__ gmax) {
    __shared__ float in4[4][260];
    __shared__ float a1s[4][256];
    __shared__ float a2s[4][512];

    const int bm0 = blockIdx.x * 4;      // first of 4 consecutive s-rows (same cloud)
    const int bcl = bm0 >> 8;            // S2CNT = 256
    const int tid = threadIdx.x;

    #pragma unroll
    for (int r = 0; r < 4; ++r) {
        in4[r][tid] = bf2f(h2[(size_t)(bm0 + r) * 256 + tid]);
        if (tid < 3) in4[r][256 + tid] = cpos2[(bm0 + r) * 3 + tid];
    }
    __syncthreads();

    {   // L1: K=259, N=256
        const float bj = b1[tid];
        float acc[4] = {bj, bj, bj, bj};
        for (int i = 0; i < 259; ++i) {
            const float w = W1[i * 256 + tid];
            #pragma unroll
            for (int r = 0; r < 4; ++r) acc[r] += in4[r][i] * w;
        }
        #pragma unroll
        for (int r = 0; r < 4; ++r) a1s[r][tid] = fmaxf(acc[r], 0.f);
    }
    __syncthreads();

    {   // L2: K=256, N=512
        const float bj0 = b2[tid], bj1 = b2[tid + 256];
        float acc0[4] = {bj0, bj0, bj0, bj0};
        float acc1[4] = {bj1, bj1, bj1, bj1};
        for (int i = 0; i < 256; ++i) {
            const float w0 = W2[i * 512 + tid];
            const float w1 = W2[i * 512 + tid + 256];
            #pragma unroll
            for (int r = 0; r < 4; ++r) {
                const float a = a1s[r][i];
                acc0[r] += a * w0;
                acc1[r] += a * w1;
            }
        }
        #pragma unroll
        for (int r = 0; r < 4; ++r) {
            a2s[r][tid]       = fmaxf(acc0[r], 0.f);
            a2s[r][tid + 256] = fmaxf(acc1[r], 0.f);
        }
    }
    __syncthreads();

    {   // L3: K=512, N=1024
        float acc[4][4];
        #pragma unroll
        for (int q = 0; q < 4; ++q) {
            const float bj = b3[tid + 256 * q];
            #pragma unroll
            for (int r = 0; r < 4; ++r) acc[q][r] = bj;
        }
        for (int i = 0; i < 512; ++i) {
            float av[4];
            #pragma unroll
            for (int r = 0; r < 4; ++r) av[r] = a2s[r][i];
            #pragma unroll
            for (int q = 0; q < 4; ++q) {
                const float w = W3[i * 1024 + 256 * q + tid];
                #pragma unroll
                for (int r = 0; r < 4; ++r) acc[q][r] += av[r] * w;
            }
        }
        #pragma unroll
        for (int q = 0; q < 4; ++q)
            #pragma unroll
            for (int r = 0; r < 4; ++r)
                atomicMax(&gmax[(size_t)bcl * 1024 + 256 * q + tid], enc_f32(acc[q][r]));
    }
}

__global__ __launch_bounds__(256) void gmax_decode_kernel(const unsigned* __restrict__ gmax,
                                                          float* __restrict__ out) {
    int t = blockIdx.x * 256 + threadIdx.x;
    unsigned u = gmax[t];
    out[t] = (u & 0x80000000u) ? __uint_as_float(u ^ 0x80000000u) : __uint_as_float(~u);
}

// ---------------------------------------------------------------------------
extern "C" void kernel_launch(void* const* d_in, const int* in_sizes, int n_in,
                              void* d_out, int out_size, void* d_ws, size_t ws_size,
                              hipStream_t stream) {
    (void)in_sizes; (void)n_in; (void)out_size; (void)ws_size;

    const float* pos = (const float*)d_in[0];
    const float* W1a = (const float*)d_in[1];  const float* b1a = (const float*)d_in[2];
    const float* W1b = (const float*)d_in[3];  const float* b1b = (const float*)d_in[4];
    const float* W1c = (const float*)d_in[5];  const float* b1c = (const float*)d_in[6];
    const float* W2a = (const float*)d_in[7];  const float* b2a = (const float*)d_in[8];
    const float* W2b = (const float*)d_in[9];  const float* b2b = (const float*)d_in[10];
    const float* W2c = (const float*)d_in[11]; const float* b2c = (const float*)d_in[12];
    const float* W3a = (const float*)d_in[13]; const float* b3a = (const float*)d_in[14];
    const float* W3b = (const float*)d_in[15]; const float* b3b = (const float*)d_in[16];
    const float* W3c = (const float*)d_in[17]; const float* b3c = (const float*)d_in[18];

    float* out = (float*)d_out;

    char* ws = (char*)d_ws;
    auto alloc = [&](size_t bytes) {
        char* p = ws;
        ws += (bytes + 255) & ~(size_t)255;
        return p;
    };
    float*    cpos1 = (float*)   alloc((size_t)B_CL * S1CNT * 3 * 4);
    int*      nbr1  = (int*)     alloc((size_t)B_CL * S1CNT * KNBR * 4);
    int*      cnt1  = (int*)     alloc((size_t)B_CL * S1CNT * 4);
    ushort*   h1    = (ushort*)  alloc((size_t)B_CL * S1CNT * 128 * 2);
    float*    cpos2 = (float*)   alloc((size_t)B_CL * S2CNT * 3 * 4);
    int*      nbr2  = (int*)     alloc((size_t)B_CL * S2CNT * KNBR * 4);
    int*      cnt2  = (int*)     alloc((size_t)B_CL * S2CNT * 4);
    ushort*   h2    = (ushort*)  alloc((size_t)B_CL * S2CNT * 256 * 2);
    unsigned* gmax  = (unsigned*)alloc((size_t)B_CL * 1024 * 4);
    ushort*   Wt1a  = (ushort*)  alloc((size_t)64  * 40  * 2);
    ushort*   Wt1b  = (ushort*)  alloc((size_t)64  * 72  * 2);
    ushort*   Wt1c  = (ushort*)  alloc((size_t)128 * 72  * 2);
    ushort*   Wt2a  = (ushort*)  alloc((size_t)128 * 168 * 2);
    ushort*   Wt2b  = (ushort*)  alloc((size_t)128 * 136 * 2);
    ushort*   Wt2c  = (ushort*)  alloc((size_t)256 * 136 * 2);

    const float RR1 = (float)(0.2 * 0.2);
    const float RR2 = (float)(0.4 * 0.4);

    // 1: FPS stage 1 (8 blocks x 256, r7 body) + 6 weight-prep blocks
    fps1_wprep_kernel<<<B_CL + 6, 256, 0, stream>>>(pos, cpos1,
                                                    W1a, Wt1a, W1b, Wt1b, W1c, Wt1c,
                                                    W2a, Wt2a, W2b, Wt2b, W2c, Wt2c);
    // 2: radius stage 1 + FPS stage 2
    radius1_fps2_kernel<<<B_CL * S1CNT + B_CL, 256, 0, stream>>>(pos, cpos1, RR1,
                                                                 nbr1, cnt1, cpos2);
    // 3: conv1 + radius stage 2
    conv1_rad2_kernel<<<B_CL * S1CNT + B_CL * S2CNT, 256, 0, stream>>>(
        pos, cpos1, nbr1, cnt1, Wt1a, b1a, Wt1b, b1b, Wt1c, b1c, h1,
        cpos2, RR2, nbr2, cnt2);
    // 4: conv2 + gmax init
    conv2_init_kernel<<<B_CL * S2CNT + (B_CL * 1024) / 256, 256, 0, stream>>>(
        h1, cpos1, cpos2, nbr2, cnt2, Wt2a, b2a, Wt2b, b2b, Wt2c, b2c, h2, gmax);
    // 5: global MLP + max pool
    mlp3_kernel<<<(B_CL * S2CNT) / 4, 256, 0, stream>>>(h2, cpos2,
                                                        W3a, b3a, W3b, b3b, W3c, b3c, gmax);
    // 6: decode
    gmax_decode_kernel<<<(B_CL * 1024) / 256, 256, 0, stream>>>(gmax, out);
}